// Round 5
// baseline (244.857 us; speedup 1.0000x reference)
//
#include <hip/hip_runtime.h>
#include <hip/hip_bf16.h>

typedef __attribute__((ext_vector_type(8))) short bf16x8;
typedef __attribute__((ext_vector_type(4))) float f32x4;

#define NPIX 8192      // 8 * 32 * 32
#define HIDC 512
#define CIN  2048

// ---------- helpers ----------
__device__ __forceinline__ ushort f2b(float f) {
    union { float f; unsigned u; } v; v.f = f;
    unsigned r = v.u + 0x7fffu + ((v.u >> 16) & 1u);   // RNE
    return (ushort)(r >> 16);
}

__device__ __forceinline__ void gload16(const void* g, void* l) {
    __builtin_amdgcn_global_load_lds(
        (const __attribute__((address_space(1))) void*)g,
        (__attribute__((address_space(3))) void*)l, 16, 0, 0);
}

// ---------- 0: zero only the halo border cells of xp ----------
// border cells per batch: y==0, y==33, x==0, x==33  -> 34+34+32+32 = 132 cells
__global__ void zero_border(ushort* __restrict__ xp) {
    int c = blockIdx.x;        // 0..131
    int b = blockIdx.y;        // 0..7
    int y, x;
    if (c < 34)      { y = 0;  x = c; }
    else if (c < 68) { y = 33; x = c - 34; }
    else if (c < 100){ y = c - 68 + 1; x = 0; }
    else             { y = c - 100 + 1; x = 33; }
    uint4* dst = (uint4*)(xp + (((size_t)b * 34 + y) * 34 + x) * CIN);
    uint4 z = {0u, 0u, 0u, 0u};
    dst[threadIdx.x] = z;      // 256 threads * 16B = 4KB = 2048 ch * 2B
}

// ---------- 1: NCHW fp32 -> padded NHWC bf16  xp[b][y+1][x+1][c] ----------
__global__ void pack_x(const float* __restrict__ x, ushort* __restrict__ xp) {
    __shared__ float tile[64][65];
    int b  = blockIdx.z;
    int c0 = blockIdx.y * 64;
    int p0 = blockIdx.x * 64;
    int t = threadIdx.x;
    int tx = t & 63, ty = t >> 6;
    const float* src = x + ((size_t)b * CIN + c0) * 1024 + p0;
    for (int i = ty; i < 64; i += 4)
        tile[i][tx] = src[(size_t)i * 1024 + tx];
    __syncthreads();
    int ci = t & 63, pj = t >> 6;
    for (int j = pj; j < 64; j += 4) {
        int p = p0 + j;
        int y = p >> 5, xx = p & 31;
        ushort* dst = xp + (((size_t)b * 34 + y + 1) * 34 + (xx + 1)) * CIN + c0;
        dst[ci] = f2b(tile[ci][j]);
    }
}

// ---------- 2: w[n][c][ky][kx] fp32 -> wpk[tap][n][c] bf16 ----------
__global__ void pack_w(const float* __restrict__ hw, ushort* __restrict__ wpk) {
    __shared__ float ld[512 * 9];
    int n = blockIdx.x;
    int t = threadIdx.x;
    const float* src = hw + (size_t)n * (CIN * 9);
    for (int cc0 = 0; cc0 < CIN; cc0 += 512) {
        for (int i = t; i < 4608; i += 256) ld[i] = src[(size_t)cc0 * 9 + i];
        __syncthreads();
        for (int t9 = 0; t9 < 9; ++t9)
            for (int idx = t; idx < 512; idx += 256)
                wpk[((size_t)(t9 * 512 + n)) * CIN + cc0 + idx] = f2b(ld[idx * 9 + t9]);
        __syncthreads();
    }
}

// ---------- 3: conf_w/reg_w -> w2b[48][512] bf16 (rows 45..47 zero) ----------
__global__ void pack_w2(const float* __restrict__ cw, const float* __restrict__ rw,
                        ushort* __restrict__ w2b) {
    int i = blockIdx.x * 256 + threadIdx.x;
    if (i >= 48 * 512) return;
    int m = i >> 9, c = i & 511;
    float v = 0.f;
    if (m < 9) v = cw[m * 512 + c];
    else if (m < 45) v = rw[(m - 9) * 512 + c];
    w2b[i] = f2b(v);
}

// ======== conv as implicit GEMM ========
// LDS slot swizzle: slot(r,kc) = (r*4+kc) ^ ((r>>1)&7); staging dest linear,
// source (r,kc) permuted with the same XOR; read applies XOR. Conflict-free.

// ---------- 4a: split-K x3, 512 threads / 8 waves -> fp32 partials ----------
#define KSTEPS_SPLIT 192   // 3 taps * 64

__launch_bounds__(512, 6)
__global__ void conv_gemm_splitk(const ushort* __restrict__ xp, const ushort* __restrict__ wpk,
                                 float* __restrict__ pp) {
    __shared__ __align__(16) ushort A0[128 * 32];   // 8KB: 128 pix-rows x 32 ch
    __shared__ __align__(16) ushort B0[128 * 32];   // 8KB: 128 n-rows  x 32 ch
    __shared__ __align__(16) ushort A1[128 * 32];
    __shared__ __align__(16) ushort B1[128 * 32];

    int t = threadIdx.x;

    // 768 blocks on 8 XCDs: per XCD 96 slots = 32 (pb,nb) pairs x 3 k-splits
    int orig = blockIdx.x;
    int xcd  = orig & 7;
    int slot = orig >> 3;          // 0..95
    int pairLocal = slot & 31;
    int ks   = slot >> 5;          // 0..2  (tap triple)
    int pair = (xcd << 5) + pairLocal;   // 0..255
    int nb = pair & 3;
    int pb = pair >> 2;
    int n0   = nb * 128;
    int pix0 = pb * 128;

    int w = t >> 6, l = t & 63;
    int wr = w >> 2;               // 0..1 : 64-row band
    int wc = w & 3;                // 0..3 : 32-col band

    // staging-side inverse swizzle: LDS slot t holds (rA, kA)
    int u  = t ^ ((t >> 3) & 7);
    int rA = u >> 2;               // 0..127
    int kA = (u & 3) * 8;

    int p1 = pix0 + rA;
    int b   = p1 >> 10;
    int py1 = (p1 >> 5) & 31, px1 = p1 & 31;
    size_t aBase1 = ((size_t)b * 34 + py1) * 34 + px1;

    f32x4 zero = {0.f, 0.f, 0.f, 0.f};
    f32x4 acc[4][2];
#pragma unroll
    for (int i = 0; i < 4; ++i)
#pragma unroll
        for (int j = 0; j < 2; ++j) acc[i][j] = zero;

    int lr = l & 15;
    int kc = l >> 4;
    int sw = ((lr * 4 + kc) ^ ((lr >> 1) & 7)) * 16;

    int tap0 = ks * 3;

    auto stage = [&](int kk, ushort* As, ushort* Bs) {
        int tap = tap0 + (kk >> 6);
        int c0 = (kk & 63) << 5;
        int dy = tap / 3, dx = tap - dy * 3;
        size_t aoff = (size_t)(dy * 34 + dx) * CIN + kA + c0;
        gload16(xp + aBase1 * CIN + aoff, (char*)As + t * 16);
        const ushort* bp = wpk + ((size_t)(tap * 512) + n0 + rA) * CIN + kA + c0;
        gload16(bp, (char*)Bs + t * 16);
    };

    auto compute = [&](const ushort* As, const ushort* Bs) {
        const char* ab = (const char*)As + wr * 4096 + sw;
        const char* bb = (const char*)Bs + wc * 2048 + sw;
        bf16x8 af[4], bfr[2];
#pragma unroll
        for (int mi = 0; mi < 4; ++mi)
            af[mi] = *(const bf16x8*)(ab + mi * 1024);
#pragma unroll
        for (int ni = 0; ni < 2; ++ni)
            bfr[ni] = *(const bf16x8*)(bb + ni * 1024);
#pragma unroll
        for (int mi = 0; mi < 4; ++mi)
#pragma unroll
            for (int ni = 0; ni < 2; ++ni)
                acc[mi][ni] = __builtin_amdgcn_mfma_f32_16x16x32_bf16(
                    af[mi], bfr[ni], acc[mi][ni], 0, 0, 0);
    };

    stage(0, A0, B0);
    __syncthreads();
    for (int kk = 0; kk < KSTEPS_SPLIT; kk += 2) {
        if (kk + 1 < KSTEPS_SPLIT) stage(kk + 1, A1, B1);
        compute(A0, B0);
        __syncthreads();
        if (kk + 2 < KSTEPS_SPLIT) stage(kk + 2, A0, B0);
        compute(A1, B1);
        __syncthreads();
    }

    float* dst = pp + (size_t)ks * NPIX * HIDC;
    int lr4 = (l >> 4) * 4;
#pragma unroll
    for (int mi = 0; mi < 4; ++mi) {
#pragma unroll
        for (int ni = 0; ni < 2; ++ni) {
            int col = n0 + wc * 32 + ni * 16 + lr;
#pragma unroll
            for (int r = 0; r < 4; ++r) {
                int row = pix0 + wr * 64 + mi * 16 + lr4 + r;
                dst[(size_t)row * HIDC + col] = acc[mi][ni][r];
            }
        }
    }
}

// ---------- 4b: reduce partials + bias + relu -> hidden bf16 ----------
__global__ void reduce_bias_relu(const float* __restrict__ pp, const float* __restrict__ hb,
                                 ushort* __restrict__ hidden) {
    int i = blockIdx.x * 256 + threadIdx.x;          // over 4M/4 float4 groups
    const float4* p0 = (const float4*)pp;
    const float4* p1 = p0 + (size_t)NPIX * HIDC / 4;
    const float4* p2 = p1 + (size_t)NPIX * HIDC / 4;
    float4 a = p0[i], b = p1[i], c = p2[i];
    int col4 = (i & 127) * 4;
    const float4 bias = *(const float4*)&hb[col4];
    ushort4 r;
    float v0 = a.x + b.x + c.x + bias.x; r.x = f2b(v0 > 0.f ? v0 : 0.f);
    float v1 = a.y + b.y + c.y + bias.y; r.y = f2b(v1 > 0.f ? v1 : 0.f);
    float v2 = a.z + b.z + c.z + bias.z; r.z = f2b(v2 > 0.f ? v2 : 0.f);
    float v3 = a.w + b.w + c.w + bias.w; r.w = f2b(v3 > 0.f ? v3 : 0.f);
    *(ushort4*)&hidden[(size_t)i * 4] = r;
}

// ---------- 4c: fallback single-pass conv (256 thr), if ws too small ----------
#define NKSTEP 576

__launch_bounds__(256, 1)
__global__ void conv_gemm(const ushort* __restrict__ xp, const ushort* __restrict__ wpk,
                          const float* __restrict__ hb, ushort* __restrict__ hidden) {
    __shared__ __align__(16) ushort A0[128 * 32];
    __shared__ __align__(16) ushort B0[128 * 32];
    __shared__ __align__(16) ushort A1[128 * 32];
    __shared__ __align__(16) ushort B1[128 * 32];

    int t = threadIdx.x;
    int orig = blockIdx.x;
    int xcd = orig & 7;
    int ix  = orig >> 3;
    int nb  = ix & 3;
    int pb  = (xcd << 3) + (ix >> 2);
    int n0   = nb * 128;
    int pix0 = pb * 128;

    int w = t >> 6, l = t & 63;
    int wr = w >> 1, wc = w & 1;

    int u  = t ^ ((t >> 3) & 7);
    int rA = u >> 2;
    int kA = (u & 3) * 8;

    int p1 = pix0 + rA, p2 = p1 + 64;
    int b   = p1 >> 10;
    int py1 = (p1 >> 5) & 31, px1 = p1 & 31;
    int py2 = (p2 >> 5) & 31, px2 = p2 & 31;

    size_t aBase1 = ((size_t)b * 34 + py1) * 34 + px1;
    size_t aBase2 = ((size_t)b * 34 + py2) * 34 + px2;

    f32x4 zero = {0.f, 0.f, 0.f, 0.f};
    f32x4 acc[4][4];
#pragma unroll
    for (int i = 0; i < 4; ++i)
#pragma unroll
        for (int j = 0; j < 4; ++j) acc[i][j] = zero;

    int lr = l & 15;
    int kc = l >> 4;
    int sw = ((lr * 4 + kc) ^ ((lr >> 1) & 7)) * 16;

    auto stage = [&](int kk, ushort* As, ushort* Bs) {
        int tap = kk >> 6;
        int c0 = (kk & 63) << 5;
        int dy = tap / 3, dx = tap - dy * 3;
        size_t aoff = (size_t)(dy * 34 + dx) * CIN + kA + c0;
        gload16(xp + aBase1 * CIN + aoff, (char*)As + t * 16);
        gload16(xp + aBase2 * CIN + aoff, (char*)As + 4096 + t * 16);
        const ushort* bp = wpk + ((size_t)(tap * 512) + n0 + rA) * CIN + kA + c0;
        gload16(bp, (char*)Bs + t * 16);
        gload16(bp + (size_t)64 * CIN, (char*)Bs + 4096 + t * 16);
    };

    auto compute = [&](const ushort* As, const ushort* Bs) {
        const char* ab = (const char*)As + wr * 4096 + sw;
        const char* bb = (const char*)Bs + wc * 4096 + sw;
        bf16x8 af[4], bfr[4];
#pragma unroll
        for (int mi = 0; mi < 4; ++mi)
            af[mi] = *(const bf16x8*)(ab + mi * 1024);
#pragma unroll
        for (int ni = 0; ni < 4; ++ni)
            bfr[ni] = *(const bf16x8*)(bb + ni * 1024);
#pragma unroll
        for (int mi = 0; mi < 4; ++mi)
#pragma unroll
            for (int ni = 0; ni < 4; ++ni)
                acc[mi][ni] = __builtin_amdgcn_mfma_f32_16x16x32_bf16(
                    af[mi], bfr[ni], acc[mi][ni], 0, 0, 0);
    };

    stage(0, A0, B0);
    __syncthreads();
    for (int kk = 0; kk < NKSTEP; kk += 2) {
        if (kk + 1 < NKSTEP) stage(kk + 1, A1, B1);
        compute(A0, B0);
        __syncthreads();
        if (kk + 2 < NKSTEP) stage(kk + 2, A0, B0);
        compute(A1, B1);
        __syncthreads();
    }

    int lr4 = (l >> 4) * 4;
#pragma unroll
    for (int mi = 0; mi < 4; ++mi) {
#pragma unroll
        for (int ni = 0; ni < 4; ++ni) {
            int col = n0 + wc * 64 + ni * 16 + lr;
            float bias = hb[col];
#pragma unroll
            for (int r = 0; r < 4; ++r) {
                int row = pix0 + wr * 64 + mi * 16 + lr4 + r;
                float v = acc[mi][ni][r] + bias;
                v = v > 0.f ? v : 0.f;
                hidden[(size_t)row * HIDC + col] = f2b(v);
            }
        }
    }
}

// ---------- 5: 1x1 convs as GEMM (N=48 incl pad), bias -> g fp32 [8192][48] ----------
__launch_bounds__(256)
__global__ void gemm2(const ushort* __restrict__ hidden, const ushort* __restrict__ w2b,
                      const float* __restrict__ cb, const float* __restrict__ rb,
                      float* __restrict__ g) {
    __shared__ __align__(16) ushort W2[48 * 520];
    int t = threadIdx.x;
    const unsigned* src = (const unsigned*)w2b;
    unsigned* dstW = (unsigned*)&W2[0];
    for (int i = t; i < 12288; i += 256) {
        int m = i >> 8, c2 = i & 255;
        dstW[m * 260 + c2] = src[i];
    }
    __syncthreads();
    int w = t >> 6, l = t & 63;
    int p0 = blockIdx.x * 64 + w * 16;
    int lr = l & 15, lk = (l >> 4) * 8;
    f32x4 zero = {0.f, 0.f, 0.f, 0.f};
    f32x4 acc[3] = {zero, zero, zero};
    const ushort* hrow = hidden + (size_t)(p0 + lr) * HIDC + lk;
#pragma unroll 4
    for (int k0 = 0; k0 < 16; ++k0) {
        bf16x8 a = *(const bf16x8*)(hrow + k0 * 32);
#pragma unroll
        for (int ni = 0; ni < 3; ++ni) {
            bf16x8 bb = *(const bf16x8*)&W2[(ni * 16 + lr) * 520 + k0 * 32 + lk];
            acc[ni] = __builtin_amdgcn_mfma_f32_16x16x32_bf16(a, bb, acc[ni], 0, 0, 0);
        }
    }
    int lr4 = (l >> 4) * 4;
#pragma unroll
    for (int ni = 0; ni < 3; ++ni) {
        int m = ni * 16 + lr;
        float bias = (m < 9) ? cb[m] : ((m < 45) ? rb[m - 9] : 0.f);
#pragma unroll
        for (int r = 0; r < 4; ++r) {
            int p = p0 + lr4 + r;
            g[(size_t)p * 48 + m] = acc[ni][r] + bias;
        }
    }
}

// ---------- 6: proposal math ----------
__global__ void proposals(const float* __restrict__ g, float* __restrict__ out) {
    int i = blockIdx.x * 256 + threadIdx.x;
    if (i >= NPIX * 9) return;
    int p = i / 9, a = i - p * 9;
    int y = (p >> 5) & 31, x = p & 31;
    int si = a / 3, ri = a - si * 3;
    float hA = 2.f * (float)(si + 1);
    float wA = (float)((si + 1) * (ri + 1));

    const float* gp = g + (size_t)p * 48;
    float conf = gp[a];
    float o0 = gp[9 + a * 4 + 0];
    float o1 = gp[9 + a * 4 + 1];
    float o2 = gp[9 + a * 4 + 2];
    float o3 = gp[9 + a * 4 + 3];

    float cx = x + 0.5f, cy = y + 0.5f;
    float x1 = fminf(fmaxf(cx - wA * 0.5f, 0.f), 32.f);
    float y1 = fminf(fmaxf(cy - hA * 0.5f, 0.f), 32.f);
    float x2 = fminf(fmaxf(cx + wA * 0.5f, 0.f), 32.f);
    float y2 = fminf(fmaxf(cy + hA * 0.5f, 0.f), 32.f);
    float aw = x2 - x1, ah = y2 - y1;
    float acx = x1 + aw * 0.5f, acy = y1 + ah * 0.5f;
    float pcx = acx + o0 * aw, pcy = acy + o1 * ah;
    float pw = aw * expf(o2), ph = ah * expf(o3);
    float s = 1.f / (1.f + expf(-conf));

    float* o = out + (size_t)i * 5;
    o[0] = s;
    o[1] = (pcx - pw * 0.5f) * 32.f;
    o[2] = (pcy - ph * 0.5f) * 32.f;
    o[3] = (pcx + pw * 0.5f) * 32.f;
    o[4] = (pcy + ph * 0.5f) * 32.f;
}

extern "C" void kernel_launch(void* const* d_in, const int* in_sizes, int n_in,
                              void* d_out, int out_size, void* d_ws, size_t ws_size,
                              hipStream_t stream) {
    const float* x  = (const float*)d_in[0];
    const float* hw = (const float*)d_in[1];
    const float* hb = (const float*)d_in[2];
    const float* cw = (const float*)d_in[3];
    const float* cb = (const float*)d_in[4];
    const float* rw = (const float*)d_in[5];
    const float* rb = (const float*)d_in[6];
    float* out = (float*)d_out;

    char* ws = (char*)d_ws;
    ushort* xp     = (ushort*)(ws);                 // 8*34*34*2048*2  = 37,879,808
    ushort* wpk    = (ushort*)(ws + 37879808);      // 9*512*2048*2   = 18,874,368
    ushort* hidden = (ushort*)(ws + 56754176);      // 8192*512*2     =  8,388,608
    ushort* w2b    = (ushort*)(ws + 65142784);      // 48*512*2       =     49,152
    float*  g      = (float*)(ws + 65191936);       // 8192*48*4      =  1,572,864
    float*  pp     = (float*)(ws + 66764800);       // 3*8192*512*4   = 50,331,648
    const size_t WS_NEED_SPLITK = 66764800 + 50331648;   // 117,096,448

    hipLaunchKernelGGL(zero_border, dim3(132, 8), dim3(256), 0, stream, xp);
    hipLaunchKernelGGL(pack_x, dim3(16, 32, 8), dim3(256), 0, stream, x, xp);
    hipLaunchKernelGGL(pack_w, dim3(512), dim3(256), 0, stream, hw, wpk);
    hipLaunchKernelGGL(pack_w2, dim3(96), dim3(256), 0, stream, cw, rw, w2b);
    if (ws_size >= WS_NEED_SPLITK) {
        hipLaunchKernelGGL(conv_gemm_splitk, dim3(768), dim3(512), 0, stream, xp, wpk, pp);
        hipLaunchKernelGGL(reduce_bias_relu, dim3(4096), dim3(256), 0, stream, pp, hb, hidden);
    } else {
        hipLaunchKernelGGL(conv_gemm, dim3(256), dim3(256), 0, stream, xp, wpk, hb, hidden);
    }
    hipLaunchKernelGGL(gemm2, dim3(128), dim3(256), 0, stream, hidden, w2b, cb, rb, g);
    hipLaunchKernelGGL(proposals, dim3(288), dim3(256), 0, stream, g, out);
}

// Round 6
// 242.570 us; speedup vs baseline: 1.0094x; 1.0094x over previous
//
#include <hip/hip_runtime.h>
#include <hip/hip_bf16.h>

typedef __attribute__((ext_vector_type(8))) short bf16x8;
typedef __attribute__((ext_vector_type(4))) float f32x4;

#define NPIX 8192      // 8 * 32 * 32
#define HIDC 512
#define CIN  2048

// ---------- helpers ----------
__device__ __forceinline__ ushort f2b(float f) {
    union { float f; unsigned u; } v; v.f = f;
    unsigned r = v.u + 0x7fffu + ((v.u >> 16) & 1u);   // RNE
    return (ushort)(r >> 16);
}

__device__ __forceinline__ void gload16(const void* g, void* l) {
    __builtin_amdgcn_global_load_lds(
        (const __attribute__((address_space(1))) void*)g,
        (__attribute__((address_space(3))) void*)l, 16, 0, 0);
}

#define WAITV4() asm volatile("s_waitcnt vmcnt(4) lgkmcnt(0)" ::: "memory")
#define WAITV0() asm volatile("s_waitcnt vmcnt(0) lgkmcnt(0)" ::: "memory")
#define BARRIER() do { asm volatile("s_barrier" ::: "memory"); \
                       __builtin_amdgcn_sched_barrier(0); } while (0)

// ---------- 0: zero only the halo border cells of xp ----------
__global__ void zero_border(ushort* __restrict__ xp) {
    int c = blockIdx.x;        // 0..131
    int b = blockIdx.y;        // 0..7
    int y, x;
    if (c < 34)      { y = 0;  x = c; }
    else if (c < 68) { y = 33; x = c - 34; }
    else if (c < 100){ y = c - 68 + 1; x = 0; }
    else             { y = c - 100 + 1; x = 33; }
    uint4* dst = (uint4*)(xp + (((size_t)b * 34 + y) * 34 + x) * CIN);
    uint4 z = {0u, 0u, 0u, 0u};
    dst[threadIdx.x] = z;
}

// ---------- 1: NCHW fp32 -> padded NHWC bf16  xp[b][y+1][x+1][c] ----------
__global__ void pack_x(const float* __restrict__ x, ushort* __restrict__ xp) {
    __shared__ float tile[64][65];
    int b  = blockIdx.z;
    int c0 = blockIdx.y * 64;
    int p0 = blockIdx.x * 64;
    int t = threadIdx.x;
    int tx = t & 63, ty = t >> 6;
    const float* src = x + ((size_t)b * CIN + c0) * 1024 + p0;
    for (int i = ty; i < 64; i += 4)
        tile[i][tx] = src[(size_t)i * 1024 + tx];
    __syncthreads();
    int ci = t & 63, pj = t >> 6;
    for (int j = pj; j < 64; j += 4) {
        int p = p0 + j;
        int y = p >> 5, xx = p & 31;
        ushort* dst = xp + (((size_t)b * 34 + y + 1) * 34 + (xx + 1)) * CIN + c0;
        dst[ci] = f2b(tile[ci][j]);
    }
}

// ---------- 2: w[n][c][ky][kx] fp32 -> wpk[tap][n][c] bf16 ----------
__global__ void pack_w(const float* __restrict__ hw, ushort* __restrict__ wpk) {
    __shared__ float ld[512 * 9];
    int n = blockIdx.x;
    int t = threadIdx.x;
    const float* src = hw + (size_t)n * (CIN * 9);
    for (int cc0 = 0; cc0 < CIN; cc0 += 512) {
        for (int i = t; i < 4608; i += 256) ld[i] = src[(size_t)cc0 * 9 + i];
        __syncthreads();
        for (int t9 = 0; t9 < 9; ++t9)
            for (int idx = t; idx < 512; idx += 256)
                wpk[((size_t)(t9 * 512 + n)) * CIN + cc0 + idx] = f2b(ld[idx * 9 + t9]);
        __syncthreads();
    }
}

// ---------- 3: conf_w/reg_w -> w2b[48][512] bf16 (rows 45..47 zero) ----------
__global__ void pack_w2(const float* __restrict__ cw, const float* __restrict__ rw,
                        ushort* __restrict__ w2b) {
    int i = blockIdx.x * 256 + threadIdx.x;
    if (i >= 48 * 512) return;
    int m = i >> 9, c = i & 511;
    float v = 0.f;
    if (m < 9) v = cw[m * 512 + c];
    else if (m < 45) v = rw[(m - 9) * 512 + c];
    w2b[i] = f2b(v);
}

// ======== conv as implicit GEMM ========
// LDS slot swizzle: slot(r,kc) = (r*4+kc) ^ ((r>>1)&7); staging dest linear,
// source (r,kc) permuted with the same XOR; read applies XOR. Conflict-free.

// ---------- 4a: split-K x3, ring-3 counted-vmcnt pipeline ----------
#define KSTEPS_SPLIT 192   // 3 taps * 64

__launch_bounds__(256, 3)
__global__ void conv_gemm_splitk(const ushort* __restrict__ xp, const ushort* __restrict__ wpk,
                                 float* __restrict__ pp) {
    __shared__ __align__(16) ushort A0[128 * 32];
    __shared__ __align__(16) ushort B0[128 * 32];
    __shared__ __align__(16) ushort A1[128 * 32];
    __shared__ __align__(16) ushort B1[128 * 32];
    __shared__ __align__(16) ushort A2[128 * 32];
    __shared__ __align__(16) ushort B2[128 * 32];

    int t = threadIdx.x;

    // 768 blocks on 8 XCDs: per XCD 96 slots = 32 (pb,nb) pairs x 3 k-splits
    int orig = blockIdx.x;
    int xcd  = orig & 7;
    int slot = orig >> 3;          // 0..95
    int pairLocal = slot & 31;
    int ks   = slot >> 5;          // 0..2  (tap triple)
    int pair = (xcd << 5) + pairLocal;   // 0..255
    int nb = pair & 3;
    int pb = pair >> 2;
    int n0   = nb * 128;
    int pix0 = pb * 128;

    int w = t >> 6, l = t & 63;
    int wr = w >> 1, wc = w & 1;

    // staging-side inverse swizzle: LDS slot t holds (rA, kA)
    int u  = t ^ ((t >> 3) & 7);
    int rA = u >> 2;
    int kA = (u & 3) * 8;

    int p1 = pix0 + rA, p2 = p1 + 64;
    int b   = p1 >> 10;
    int py1 = (p1 >> 5) & 31, px1 = p1 & 31;
    int py2 = (p2 >> 5) & 31, px2 = p2 & 31;

    size_t aBase1 = ((size_t)b * 34 + py1) * 34 + px1;
    size_t aBase2 = ((size_t)b * 34 + py2) * 34 + px2;

    f32x4 zero = {0.f, 0.f, 0.f, 0.f};
    f32x4 acc[4][4];
#pragma unroll
    for (int i = 0; i < 4; ++i)
#pragma unroll
        for (int j = 0; j < 4; ++j) acc[i][j] = zero;

    int lr = l & 15;
    int kc = l >> 4;
    int sw = ((lr * 4 + kc) ^ ((lr >> 1) & 7)) * 16;

    int tap0 = ks * 3;

    auto stage = [&](int kk, ushort* As, ushort* Bs) {
        int tap = tap0 + (kk >> 6);
        int c0 = (kk & 63) << 5;
        int dy = tap / 3, dx = tap - dy * 3;
        size_t aoff = (size_t)(dy * 34 + dx) * CIN + kA + c0;
        gload16(xp + aBase1 * CIN + aoff, (char*)As + t * 16);
        gload16(xp + aBase2 * CIN + aoff, (char*)As + 4096 + t * 16);
        const ushort* bp = wpk + ((size_t)(tap * 512) + n0 + rA) * CIN + kA + c0;
        gload16(bp, (char*)Bs + t * 16);
        gload16(bp + (size_t)64 * CIN, (char*)Bs + 4096 + t * 16);
    };

    auto compute = [&](const ushort* As, const ushort* Bs) {
        const char* ab = (const char*)As + wr * 4096 + sw;
        const char* bb = (const char*)Bs + wc * 4096 + sw;
        bf16x8 af[4], bfr[4];
#pragma unroll
        for (int mi = 0; mi < 4; ++mi)
            af[mi] = *(const bf16x8*)(ab + mi * 1024);
#pragma unroll
        for (int ni = 0; ni < 4; ++ni)
            bfr[ni] = *(const bf16x8*)(bb + ni * 1024);
#pragma unroll
        for (int mi = 0; mi < 4; ++mi)
#pragma unroll
            for (int ni = 0; ni < 4; ++ni)
                acc[mi][ni] = __builtin_amdgcn_mfma_f32_16x16x32_bf16(
                    af[mi], bfr[ni], acc[mi][ni], 0, 0, 0);
    };

    // ring-3 pipeline: buf(k) = k % 3. One barrier per step; vmcnt never
    // drains to 0 in steady state (buf k+1's 4 loads stay in flight).
    stage(0, A0, B0);
    stage(1, A1, B1);
    for (int kk = 0; kk < KSTEPS_SPLIT - 3; kk += 3) {
        WAITV4(); BARRIER();
        stage(kk + 2, A2, B2);
        compute(A0, B0);

        WAITV4(); BARRIER();
        stage(kk + 3, A0, B0);
        compute(A1, B1);

        WAITV4(); BARRIER();
        stage(kk + 4, A1, B1);
        compute(A2, B2);
    }
    // tail: steps 189, 190, 191
    WAITV4(); BARRIER();
    stage(KSTEPS_SPLIT - 1, A2, B2);
    compute(A0, B0);

    WAITV4(); BARRIER();
    compute(A1, B1);

    WAITV0(); BARRIER();
    compute(A2, B2);

    float* dst = pp + (size_t)ks * NPIX * HIDC;
    int lr4 = (l >> 4) * 4;
#pragma unroll
    for (int mi = 0; mi < 4; ++mi) {
#pragma unroll
        for (int ni = 0; ni < 4; ++ni) {
            int col = n0 + wc * 64 + ni * 16 + lr;
#pragma unroll
            for (int r = 0; r < 4; ++r) {
                int row = pix0 + wr * 64 + mi * 16 + lr4 + r;
                dst[(size_t)row * HIDC + col] = acc[mi][ni][r];
            }
        }
    }
}

// ---------- 4b: reduce partials + bias + relu -> hidden bf16 ----------
__global__ void reduce_bias_relu(const float* __restrict__ pp, const float* __restrict__ hb,
                                 ushort* __restrict__ hidden) {
    int i = blockIdx.x * 256 + threadIdx.x;
    const float4* p0 = (const float4*)pp;
    const float4* p1 = p0 + (size_t)NPIX * HIDC / 4;
    const float4* p2 = p1 + (size_t)NPIX * HIDC / 4;
    float4 a = p0[i], b = p1[i], c = p2[i];
    int col4 = (i & 127) * 4;
    const float4 bias = *(const float4*)&hb[col4];
    ushort4 r;
    float v0 = a.x + b.x + c.x + bias.x; r.x = f2b(v0 > 0.f ? v0 : 0.f);
    float v1 = a.y + b.y + c.y + bias.y; r.y = f2b(v1 > 0.f ? v1 : 0.f);
    float v2 = a.z + b.z + c.z + bias.z; r.z = f2b(v2 > 0.f ? v2 : 0.f);
    float v3 = a.w + b.w + c.w + bias.w; r.w = f2b(v3 > 0.f ? v3 : 0.f);
    *(ushort4*)&hidden[(size_t)i * 4] = r;
}

// ---------- 4c: fallback single-pass conv (256 thr), if ws too small ----------
#define NKSTEP 576

__launch_bounds__(256, 1)
__global__ void conv_gemm(const ushort* __restrict__ xp, const ushort* __restrict__ wpk,
                          const float* __restrict__ hb, ushort* __restrict__ hidden) {
    __shared__ __align__(16) ushort A0[128 * 32];
    __shared__ __align__(16) ushort B0[128 * 32];
    __shared__ __align__(16) ushort A1[128 * 32];
    __shared__ __align__(16) ushort B1[128 * 32];

    int t = threadIdx.x;
    int orig = blockIdx.x;
    int xcd = orig & 7;
    int ix  = orig >> 3;
    int nb  = ix & 3;
    int pb  = (xcd << 3) + (ix >> 2);
    int n0   = nb * 128;
    int pix0 = pb * 128;

    int w = t >> 6, l = t & 63;
    int wr = w >> 1, wc = w & 1;

    int u  = t ^ ((t >> 3) & 7);
    int rA = u >> 2;
    int kA = (u & 3) * 8;

    int p1 = pix0 + rA, p2 = p1 + 64;
    int b   = p1 >> 10;
    int py1 = (p1 >> 5) & 31, px1 = p1 & 31;
    int py2 = (p2 >> 5) & 31, px2 = p2 & 31;

    size_t aBase1 = ((size_t)b * 34 + py1) * 34 + px1;
    size_t aBase2 = ((size_t)b * 34 + py2) * 34 + px2;

    f32x4 zero = {0.f, 0.f, 0.f, 0.f};
    f32x4 acc[4][4];
#pragma unroll
    for (int i = 0; i < 4; ++i)
#pragma unroll
        for (int j = 0; j < 4; ++j) acc[i][j] = zero;

    int lr = l & 15;
    int kc = l >> 4;
    int sw = ((lr * 4 + kc) ^ ((lr >> 1) & 7)) * 16;

    auto stage = [&](int kk, ushort* As, ushort* Bs) {
        int tap = kk >> 6;
        int c0 = (kk & 63) << 5;
        int dy = tap / 3, dx = tap - dy * 3;
        size_t aoff = (size_t)(dy * 34 + dx) * CIN + kA + c0;
        gload16(xp + aBase1 * CIN + aoff, (char*)As + t * 16);
        gload16(xp + aBase2 * CIN + aoff, (char*)As + 4096 + t * 16);
        const ushort* bp = wpk + ((size_t)(tap * 512) + n0 + rA) * CIN + kA + c0;
        gload16(bp, (char*)Bs + t * 16);
        gload16(bp + (size_t)64 * CIN, (char*)Bs + 4096 + t * 16);
    };

    auto compute = [&](const ushort* As, const ushort* Bs) {
        const char* ab = (const char*)As + wr * 4096 + sw;
        const char* bb = (const char*)Bs + wc * 4096 + sw;
        bf16x8 af[4], bfr[4];
#pragma unroll
        for (int mi = 0; mi < 4; ++mi)
            af[mi] = *(const bf16x8*)(ab + mi * 1024);
#pragma unroll
        for (int ni = 0; ni < 4; ++ni)
            bfr[ni] = *(const bf16x8*)(bb + ni * 1024);
#pragma unroll
        for (int mi = 0; mi < 4; ++mi)
#pragma unroll
            for (int ni = 0; ni < 4; ++ni)
                acc[mi][ni] = __builtin_amdgcn_mfma_f32_16x16x32_bf16(
                    af[mi], bfr[ni], acc[mi][ni], 0, 0, 0);
    };

    stage(0, A0, B0);
    __syncthreads();
    for (int kk = 0; kk < NKSTEP; kk += 2) {
        if (kk + 1 < NKSTEP) stage(kk + 1, A1, B1);
        compute(A0, B0);
        __syncthreads();
        if (kk + 2 < NKSTEP) stage(kk + 2, A0, B0);
        compute(A1, B1);
        __syncthreads();
    }

    int lr4 = (l >> 4) * 4;
#pragma unroll
    for (int mi = 0; mi < 4; ++mi) {
#pragma unroll
        for (int ni = 0; ni < 4; ++ni) {
            int col = n0 + wc * 64 + ni * 16 + lr;
            float bias = hb[col];
#pragma unroll
            for (int r = 0; r < 4; ++r) {
                int row = pix0 + wr * 64 + mi * 16 + lr4 + r;
                float v = acc[mi][ni][r] + bias;
                v = v > 0.f ? v : 0.f;
                hidden[(size_t)row * HIDC + col] = f2b(v);
            }
        }
    }
}

// ---------- 5: 1x1 convs as GEMM (N=48 incl pad), bias -> g fp32 [8192][48] ----------
__launch_bounds__(256)
__global__ void gemm2(const ushort* __restrict__ hidden, const ushort* __restrict__ w2b,
                      const float* __restrict__ cb, const float* __restrict__ rb,
                      float* __restrict__ g) {
    __shared__ __align__(16) ushort W2[48 * 520];
    int t = threadIdx.x;
    const unsigned* src = (const unsigned*)w2b;
    unsigned* dstW = (unsigned*)&W2[0];
    for (int i = t; i < 12288; i += 256) {
        int m = i >> 8, c2 = i & 255;
        dstW[m * 260 + c2] = src[i];
    }
    __syncthreads();
    int w = t >> 6, l = t & 63;
    int p0 = blockIdx.x * 64 + w * 16;
    int lr = l & 15, lk = (l >> 4) * 8;
    f32x4 zero = {0.f, 0.f, 0.f, 0.f};
    f32x4 acc[3] = {zero, zero, zero};
    const ushort* hrow = hidden + (size_t)(p0 + lr) * HIDC + lk;
#pragma unroll 4
    for (int k0 = 0; k0 < 16; ++k0) {
        bf16x8 a = *(const bf16x8*)(hrow + k0 * 32);
#pragma unroll
        for (int ni = 0; ni < 3; ++ni) {
            bf16x8 bb = *(const bf16x8*)&W2[(ni * 16 + lr) * 520 + k0 * 32 + lk];
            acc[ni] = __builtin_amdgcn_mfma_f32_16x16x32_bf16(a, bb, acc[ni], 0, 0, 0);
        }
    }
    int lr4 = (l >> 4) * 4;
#pragma unroll
    for (int ni = 0; ni < 3; ++ni) {
        int m = ni * 16 + lr;
        float bias = (m < 9) ? cb[m] : ((m < 45) ? rb[m - 9] : 0.f);
#pragma unroll
        for (int r = 0; r < 4; ++r) {
            int p = p0 + lr4 + r;
            g[(size_t)p * 48 + m] = acc[ni][r] + bias;
        }
    }
}

// ---------- 6: proposal math ----------
__global__ void proposals(const float* __restrict__ g, float* __restrict__ out) {
    int i = blockIdx.x * 256 + threadIdx.x;
    if (i >= NPIX * 9) return;
    int p = i / 9, a = i - p * 9;
    int y = (p >> 5) & 31, x = p & 31;
    int si = a / 3, ri = a - si * 3;
    float hA = 2.f * (float)(si + 1);
    float wA = (float)((si + 1) * (ri + 1));

    const float* gp = g + (size_t)p * 48;
    float conf = gp[a];
    float o0 = gp[9 + a * 4 + 0];
    float o1 = gp[9 + a * 4 + 1];
    float o2 = gp[9 + a * 4 + 2];
    float o3 = gp[9 + a * 4 + 3];

    float cx = x + 0.5f, cy = y + 0.5f;
    float x1 = fminf(fmaxf(cx - wA * 0.5f, 0.f), 32.f);
    float y1 = fminf(fmaxf(cy - hA * 0.5f, 0.f), 32.f);
    float x2 = fminf(fmaxf(cx + wA * 0.5f, 0.f), 32.f);
    float y2 = fminf(fmaxf(cy + hA * 0.5f, 0.f), 32.f);
    float aw = x2 - x1, ah = y2 - y1;
    float acx = x1 + aw * 0.5f, acy = y1 + ah * 0.5f;
    float pcx = acx + o0 * aw, pcy = acy + o1 * ah;
    float pw = aw * expf(o2), ph = ah * expf(o3);
    float s = 1.f / (1.f + expf(-conf));

    float* o = out + (size_t)i * 5;
    o[0] = s;
    o[1] = (pcx - pw * 0.5f) * 32.f;
    o[2] = (pcy - ph * 0.5f) * 32.f;
    o[3] = (pcx + pw * 0.5f) * 32.f;
    o[4] = (pcy + ph * 0.5f) * 32.f;
}

extern "C" void kernel_launch(void* const* d_in, const int* in_sizes, int n_in,
                              void* d_out, int out_size, void* d_ws, size_t ws_size,
                              hipStream_t stream) {
    const float* x  = (const float*)d_in[0];
    const float* hw = (const float*)d_in[1];
    const float* hb = (const float*)d_in[2];
    const float* cw = (const float*)d_in[3];
    const float* cb = (const float*)d_in[4];
    const float* rw = (const float*)d_in[5];
    const float* rb = (const float*)d_in[6];
    float* out = (float*)d_out;

    char* ws = (char*)d_ws;
    ushort* xp     = (ushort*)(ws);                 // 8*34*34*2048*2  = 37,879,808
    ushort* wpk    = (ushort*)(ws + 37879808);      // 9*512*2048*2   = 18,874,368
    ushort* hidden = (ushort*)(ws + 56754176);      // 8192*512*2     =  8,388,608
    ushort* w2b    = (ushort*)(ws + 65142784);      // 48*512*2       =     49,152
    float*  g      = (float*)(ws + 65191936);       // 8192*48*4      =  1,572,864
    float*  pp     = (float*)(ws + 66764800);       // 3*8192*512*4   = 50,331,648
    const size_t WS_NEED_SPLITK = 66764800 + 50331648;   // 117,096,448

    hipLaunchKernelGGL(zero_border, dim3(132, 8), dim3(256), 0, stream, xp);
    hipLaunchKernelGGL(pack_x, dim3(16, 32, 8), dim3(256), 0, stream, x, xp);
    hipLaunchKernelGGL(pack_w, dim3(512), dim3(256), 0, stream, hw, wpk);
    hipLaunchKernelGGL(pack_w2, dim3(96), dim3(256), 0, stream, cw, rw, w2b);
    if (ws_size >= WS_NEED_SPLITK) {
        hipLaunchKernelGGL(conv_gemm_splitk, dim3(768), dim3(256), 0, stream, xp, wpk, pp);
        hipLaunchKernelGGL(reduce_bias_relu, dim3(4096), dim3(256), 0, stream, pp, hb, hidden);
    } else {
        hipLaunchKernelGGL(conv_gemm, dim3(256), dim3(256), 0, stream, xp, wpk, hb, hidden);
    }
    hipLaunchKernelGGL(gemm2, dim3(128), dim3(256), 0, stream, hidden, w2b, cb, rb, g);
    hipLaunchKernelGGL(proposals, dim3(288), dim3(256), 0, stream, g, out);
}

// Round 7
// 221.438 us; speedup vs baseline: 1.1058x; 1.0954x over previous
//
#include <hip/hip_runtime.h>
#include <hip/hip_bf16.h>

typedef __attribute__((ext_vector_type(8))) short bf16x8;
typedef __attribute__((ext_vector_type(4))) float f32x4;

#define NPIX 8192      // 8 * 32 * 32
#define HIDC 512
#define CIN  2048

// ---------- helpers ----------
__device__ __forceinline__ ushort f2b(float f) {
    union { float f; unsigned u; } v; v.f = f;
    unsigned r = v.u + 0x7fffu + ((v.u >> 16) & 1u);   // RNE
    return (ushort)(r >> 16);
}

__device__ __forceinline__ void gload16(const void* g, void* l) {
    __builtin_amdgcn_global_load_lds(
        (const __attribute__((address_space(1))) void*)g,
        (__attribute__((address_space(3))) void*)l, 16, 0, 0);
}

#define WAITV6() asm volatile("s_waitcnt vmcnt(6)" ::: "memory")
#define WAITV0() asm volatile("s_waitcnt vmcnt(0)" ::: "memory")
#define BAR() do { asm volatile("s_barrier" ::: "memory"); \
                   __builtin_amdgcn_sched_barrier(0); } while (0)

// ---------- 0: zero only the halo border cells of xp ----------
__global__ void zero_border(ushort* __restrict__ xp) {
    int c = blockIdx.x;        // 0..131
    int b = blockIdx.y;        // 0..7
    int y, x;
    if (c < 34)      { y = 0;  x = c; }
    else if (c < 68) { y = 33; x = c - 34; }
    else if (c < 100){ y = c - 68 + 1; x = 0; }
    else             { y = c - 100 + 1; x = 33; }
    uint4* dst = (uint4*)(xp + (((size_t)b * 34 + y) * 34 + x) * CIN);
    uint4 z = {0u, 0u, 0u, 0u};
    dst[threadIdx.x] = z;
}

// ---------- 1: NCHW fp32 -> padded NHWC bf16  xp[b][y+1][x+1][c] ----------
__global__ void pack_x(const float* __restrict__ x, ushort* __restrict__ xp) {
    __shared__ float tile[64][65];
    int b  = blockIdx.z;
    int c0 = blockIdx.y * 64;
    int p0 = blockIdx.x * 64;
    int t = threadIdx.x;
    int tx = t & 63, ty = t >> 6;
    const float* src = x + ((size_t)b * CIN + c0) * 1024 + p0;
    for (int i = ty; i < 64; i += 4)
        tile[i][tx] = src[(size_t)i * 1024 + tx];
    __syncthreads();
    int ci = t & 63, pj = t >> 6;
    for (int j = pj; j < 64; j += 4) {
        int p = p0 + j;
        int y = p >> 5, xx = p & 31;
        ushort* dst = xp + (((size_t)b * 34 + y + 1) * 34 + (xx + 1)) * CIN + c0;
        dst[ci] = f2b(tile[ci][j]);
    }
}

// ---------- 2: w[n][c][ky][kx] fp32 -> wpk[tap][n][c] bf16 ----------
__global__ void pack_w(const float* __restrict__ hw, ushort* __restrict__ wpk) {
    __shared__ float ld[512 * 9];
    int n = blockIdx.x;
    int t = threadIdx.x;
    const float* src = hw + (size_t)n * (CIN * 9);
    for (int cc0 = 0; cc0 < CIN; cc0 += 512) {
        for (int i = t; i < 4608; i += 256) ld[i] = src[(size_t)cc0 * 9 + i];
        __syncthreads();
        for (int t9 = 0; t9 < 9; ++t9)
            for (int idx = t; idx < 512; idx += 256)
                wpk[((size_t)(t9 * 512 + n)) * CIN + cc0 + idx] = f2b(ld[idx * 9 + t9]);
        __syncthreads();
    }
}

// ---------- 3: conf_w/reg_w -> w2b[48][512] bf16 (rows 45..47 zero) ----------
__global__ void pack_w2(const float* __restrict__ cw, const float* __restrict__ rw,
                        ushort* __restrict__ w2b) {
    int i = blockIdx.x * 256 + threadIdx.x;
    if (i >= 48 * 512) return;
    int m = i >> 9, c = i & 511;
    float v = 0.f;
    if (m < 9) v = cw[m * 512 + c];
    else if (m < 45) v = rw[(m - 9) * 512 + c];
    w2b[i] = f2b(v);
}

// ======== 4a: conv implicit GEMM, 256x128 tile, 8 waves, BK=64 ========
// LDS row = 64 ch = 128 B = 8 chunks of 16B. Stored chunk for (row r, data
// chunk c) = c ^ (r&7)  -> 16-lane frag reads (rows r..r+15, fixed c) spread
// over 8 bank-quads 2-way (free). Staging dest LINEAR (slot = t + 512*j);
// source chunk pre-permuted with the same XOR (rule #21).
// Pipeline: dbuf K-tiles; per tile: [vmcnt(6); bar; P0; P1; bar; stage(i+2)].
// vmcnt never drains to 0 mid-loop (T4); setprio around MFMA clusters (T5).
#define NT_SPLIT 144   // 9216 ch per split / 64

__launch_bounds__(512, 2)
__global__ void conv_gemm_splitk(const ushort* __restrict__ xp, const ushort* __restrict__ wpk,
                                 float* __restrict__ pp) {
    __shared__ __align__(16) ushort A0[256 * 64];   // 32 KB
    __shared__ __align__(16) ushort B0[128 * 64];   // 16 KB
    __shared__ __align__(16) ushort A1[256 * 64];
    __shared__ __align__(16) ushort B1[128 * 64];

    int t = threadIdx.x;

    // 256 blocks: xcd = bid&7; per XCD 32 = 4 M-tiles x 4 N-tiles x 2 ks
    int bid = blockIdx.x;
    int xcd = bid & 7;
    int s   = bid >> 3;            // 0..31
    int ks  = s >> 4;              // 0..1  K-split
    int rem = s & 15;
    int nt  = rem & 3;             // 0..3
    int mt  = (xcd << 2) + (rem >> 2);   // 0..31
    int pix0 = mt * 256;
    int n0   = nt * 128;

    int w = t >> 6, l = t & 63;
    int wr = w >> 1;               // 0..3 : 64-pix band
    int wc = w & 1;                // 0..1 : 64-col band

    // ---- staging geometry: thread t covers A slots t+512j (j=0..3),
    //      B slots t+512j (j=0..1); row r = t>>3 + 64j; data chunk constant.
    int r0 = t >> 3;                       // 0..63
    int cOff = ((t & 7) ^ (r0 & 7)) * 8;   // data chunk * 8 ch

    int aRowBase[4];
#pragma unroll
    for (int j = 0; j < 4; ++j) {
        int p = pix0 + r0 + 64 * j;
        int b = p >> 10, py = (p >> 5) & 31, px = p & 31;
        aRowBase[j] = ((b * 34 + py) * 34 + px) * CIN;
    }
    int bRowBase[2];
#pragma unroll
    for (int j = 0; j < 2; ++j)
        bRowBase[j] = (n0 + r0 + 64 * j) * CIN;

    int ksBase = ks * 9216;

    f32x4 zero = {0.f, 0.f, 0.f, 0.f};
    f32x4 acc[4][4];
#pragma unroll
    for (int i = 0; i < 4; ++i)
#pragma unroll
        for (int j = 0; j < 4; ++j) acc[i][j] = zero;

    // ---- frag-read addressing (per-lane constants) ----
    int lr = l & 15;
    int swz0 = (((l >> 4)) ^ (lr & 7)) * 16;        // kk=0 chunk
    int swz1 = (((l >> 4) + 4) ^ (lr & 7)) * 16;    // kk=1 chunk
    int aRowByte = (wr * 64 + lr) * 128;
    int bRowByte = (wc * 64 + lr) * 128;

    auto stage = [&](int kt, ushort* As, ushort* Bs) {
        int flatk = ksBase + kt * 64;
        int tap = flatk >> 11;
        int chc = flatk & 2047;
        int dy = tap / 3, dx = tap - dy * 3;
        int aoff = (dy * 34 + dx) * CIN + chc + cOff;
#pragma unroll
        for (int j = 0; j < 4; ++j)
            gload16(xp + aRowBase[j] + aoff, (char*)As + (t + 512 * j) * 16);
        int boff = tap * (512 * CIN) + chc + cOff;
#pragma unroll
        for (int j = 0; j < 2; ++j)
            gload16(wpk + bRowBase[j] + boff, (char*)Bs + (t + 512 * j) * 16);
    };

    auto phase = [&](const ushort* As, const ushort* Bs, int kk) {
        int sz = kk ? swz1 : swz0;
        const char* ab = (const char*)As + aRowByte + sz;
        const char* bb = (const char*)Bs + bRowByte + sz;
        bf16x8 af[4], bfr[4];
#pragma unroll
        for (int mi = 0; mi < 4; ++mi)
            af[mi] = *(const bf16x8*)(ab + mi * 2048);
#pragma unroll
        for (int ni = 0; ni < 4; ++ni)
            bfr[ni] = *(const bf16x8*)(bb + ni * 2048);
        __builtin_amdgcn_s_setprio(1);
#pragma unroll
        for (int mi = 0; mi < 4; ++mi)
#pragma unroll
            for (int ni = 0; ni < 4; ++ni)
                acc[mi][ni] = __builtin_amdgcn_mfma_f32_16x16x32_bf16(
                    af[mi], bfr[ni], acc[mi][ni], 0, 0, 0);
        __builtin_amdgcn_s_setprio(0);
    };

    stage(0, A0, B0);
    stage(1, A1, B1);
    for (int i = 0; i <= NT_SPLIT - 4; i += 2) {
        WAITV6(); BAR();
        phase(A0, B0, 0); phase(A0, B0, 1);
        BAR();
        stage(i + 2, A0, B0);

        WAITV6(); BAR();
        phase(A1, B1, 0); phase(A1, B1, 1);
        BAR();
        stage(i + 3, A1, B1);
    }
    // tiles NT-2 (buf0), NT-1 (buf1): no more staging
    WAITV6(); BAR();
    phase(A0, B0, 0); phase(A0, B0, 1);
    BAR();
    WAITV0(); BAR();
    phase(A1, B1, 0); phase(A1, B1, 1);

    float* dst = pp + (size_t)ks * NPIX * HIDC;
    int lr4 = (l >> 4) * 4;
#pragma unroll
    for (int mi = 0; mi < 4; ++mi) {
#pragma unroll
        for (int ni = 0; ni < 4; ++ni) {
            int col = n0 + wc * 64 + ni * 16 + lr;
#pragma unroll
            for (int r = 0; r < 4; ++r) {
                int row = pix0 + wr * 64 + mi * 16 + lr4 + r;
                dst[(size_t)row * HIDC + col] = acc[mi][ni][r];
            }
        }
    }
}

// ---------- 4b: reduce 2 partials + bias + relu -> hidden bf16 ----------
__global__ void reduce_bias_relu(const float* __restrict__ pp, const float* __restrict__ hb,
                                 ushort* __restrict__ hidden) {
    int i = blockIdx.x * 256 + threadIdx.x;
    const float4* p0 = (const float4*)pp;
    const float4* p1 = p0 + (size_t)NPIX * HIDC / 4;
    float4 a = p0[i], b = p1[i];
    int col4 = (i & 127) * 4;
    const float4 bias = *(const float4*)&hb[col4];
    ushort4 r;
    float v0 = a.x + b.x + bias.x; r.x = f2b(v0 > 0.f ? v0 : 0.f);
    float v1 = a.y + b.y + bias.y; r.y = f2b(v1 > 0.f ? v1 : 0.f);
    float v2 = a.z + b.z + bias.z; r.z = f2b(v2 > 0.f ? v2 : 0.f);
    float v3 = a.w + b.w + bias.w; r.w = f2b(v3 > 0.f ? v3 : 0.f);
    *(ushort4*)&hidden[(size_t)i * 4] = r;
}

// ---------- 4c: fallback single-pass conv (256 thr), if ws too small ----------
#define NKSTEP 576

__launch_bounds__(256, 1)
__global__ void conv_gemm(const ushort* __restrict__ xp, const ushort* __restrict__ wpk,
                          const float* __restrict__ hb, ushort* __restrict__ hidden) {
    __shared__ __align__(16) ushort A0[128 * 32];
    __shared__ __align__(16) ushort B0[128 * 32];
    __shared__ __align__(16) ushort A1[128 * 32];
    __shared__ __align__(16) ushort B1[128 * 32];

    int t = threadIdx.x;
    int orig = blockIdx.x;
    int xcd = orig & 7;
    int ix  = orig >> 3;
    int nb  = ix & 3;
    int pb  = (xcd << 3) + (ix >> 2);
    int n0   = nb * 128;
    int pix0 = pb * 128;

    int w = t >> 6, l = t & 63;
    int wr = w >> 1, wc = w & 1;

    int u  = t ^ ((t >> 3) & 7);
    int rA = u >> 2;
    int kA = (u & 3) * 8;

    int p1 = pix0 + rA, p2 = p1 + 64;
    int b   = p1 >> 10;
    int py1 = (p1 >> 5) & 31, px1 = p1 & 31;
    int py2 = (p2 >> 5) & 31, px2 = p2 & 31;

    size_t aBase1 = ((size_t)b * 34 + py1) * 34 + px1;
    size_t aBase2 = ((size_t)b * 34 + py2) * 34 + px2;

    f32x4 zero = {0.f, 0.f, 0.f, 0.f};
    f32x4 acc[4][4];
#pragma unroll
    for (int i = 0; i < 4; ++i)
#pragma unroll
        for (int j = 0; j < 4; ++j) acc[i][j] = zero;

    int lr = l & 15;
    int kc = l >> 4;
    int sw = ((lr * 4 + kc) ^ ((lr >> 1) & 7)) * 16;

    auto stage = [&](int kk, ushort* As, ushort* Bs) {
        int tap = kk >> 6;
        int c0 = (kk & 63) << 5;
        int dy = tap / 3, dx = tap - dy * 3;
        size_t aoff = (size_t)(dy * 34 + dx) * CIN + kA + c0;
        gload16(xp + aBase1 * CIN + aoff, (char*)As + t * 16);
        gload16(xp + aBase2 * CIN + aoff, (char*)As + 4096 + t * 16);
        const ushort* bp = wpk + ((size_t)(tap * 512) + n0 + rA) * CIN + kA + c0;
        gload16(bp, (char*)Bs + t * 16);
        gload16(bp + (size_t)64 * CIN, (char*)Bs + 4096 + t * 16);
    };

    auto compute = [&](const ushort* As, const ushort* Bs) {
        const char* ab = (const char*)As + wr * 4096 + sw;
        const char* bb = (const char*)Bs + wc * 4096 + sw;
        bf16x8 af[4], bfr[4];
#pragma unroll
        for (int mi = 0; mi < 4; ++mi)
            af[mi] = *(const bf16x8*)(ab + mi * 1024);
#pragma unroll
        for (int ni = 0; ni < 4; ++ni)
            bfr[ni] = *(const bf16x8*)(bb + ni * 1024);
#pragma unroll
        for (int mi = 0; mi < 4; ++mi)
#pragma unroll
            for (int ni = 0; ni < 4; ++ni)
                acc[mi][ni] = __builtin_amdgcn_mfma_f32_16x16x32_bf16(
                    af[mi], bfr[ni], acc[mi][ni], 0, 0, 0);
    };

    stage(0, A0, B0);
    __syncthreads();
    for (int kk = 0; kk < NKSTEP; kk += 2) {
        if (kk + 1 < NKSTEP) stage(kk + 1, A1, B1);
        compute(A0, B0);
        __syncthreads();
        if (kk + 2 < NKSTEP) stage(kk + 2, A0, B0);
        compute(A1, B1);
        __syncthreads();
    }

    int lr4 = (l >> 4) * 4;
#pragma unroll
    for (int mi = 0; mi < 4; ++mi) {
#pragma unroll
        for (int ni = 0; ni < 4; ++ni) {
            int col = n0 + wc * 64 + ni * 16 + lr;
            float bias = hb[col];
#pragma unroll
            for (int r = 0; r < 4; ++r) {
                int row = pix0 + wr * 64 + mi * 16 + lr4 + r;
                float v = acc[mi][ni][r] + bias;
                v = v > 0.f ? v : 0.f;
                hidden[(size_t)row * HIDC + col] = f2b(v);
            }
        }
    }
}

// ---------- 5: 1x1 convs as GEMM (N=48 incl pad), bias -> g fp32 [8192][48] ----------
__launch_bounds__(256)
__global__ void gemm2(const ushort* __restrict__ hidden, const ushort* __restrict__ w2b,
                      const float* __restrict__ cb, const float* __restrict__ rb,
                      float* __restrict__ g) {
    __shared__ __align__(16) ushort W2[48 * 520];
    int t = threadIdx.x;
    const unsigned* src = (const unsigned*)w2b;
    unsigned* dstW = (unsigned*)&W2[0];
    for (int i = t; i < 12288; i += 256) {
        int m = i >> 8, c2 = i & 255;
        dstW[m * 260 + c2] = src[i];
    }
    __syncthreads();
    int w = t >> 6, l = t & 63;
    int p0 = blockIdx.x * 64 + w * 16;
    int lr = l & 15, lk = (l >> 4) * 8;
    f32x4 zero = {0.f, 0.f, 0.f, 0.f};
    f32x4 acc[3] = {zero, zero, zero};
    const ushort* hrow = hidden + (size_t)(p0 + lr) * HIDC + lk;
#pragma unroll 4
    for (int k0 = 0; k0 < 16; ++k0) {
        bf16x8 a = *(const bf16x8*)(hrow + k0 * 32);
#pragma unroll
        for (int ni = 0; ni < 3; ++ni) {
            bf16x8 bb = *(const bf16x8*)&W2[(ni * 16 + lr) * 520 + k0 * 32 + lk];
            acc[ni] = __builtin_amdgcn_mfma_f32_16x16x32_bf16(a, bb, acc[ni], 0, 0, 0);
        }
    }
    int lr4 = (l >> 4) * 4;
#pragma unroll
    for (int ni = 0; ni < 3; ++ni) {
        int m = ni * 16 + lr;
        float bias = (m < 9) ? cb[m] : ((m < 45) ? rb[m - 9] : 0.f);
#pragma unroll
        for (int r = 0; r < 4; ++r) {
            int p = p0 + lr4 + r;
            g[(size_t)p * 48 + m] = acc[ni][r] + bias;
        }
    }
}

// ---------- 6: proposal math ----------
__global__ void proposals(const float* __restrict__ g, float* __restrict__ out) {
    int i = blockIdx.x * 256 + threadIdx.x;
    if (i >= NPIX * 9) return;
    int p = i / 9, a = i - p * 9;
    int y = (p >> 5) & 31, x = p & 31;
    int si = a / 3, ri = a - si * 3;
    float hA = 2.f * (float)(si + 1);
    float wA = (float)((si + 1) * (ri + 1));

    const float* gp = g + (size_t)p * 48;
    float conf = gp[a];
    float o0 = gp[9 + a * 4 + 0];
    float o1 = gp[9 + a * 4 + 1];
    float o2 = gp[9 + a * 4 + 2];
    float o3 = gp[9 + a * 4 + 3];

    float cx = x + 0.5f, cy = y + 0.5f;
    float x1 = fminf(fmaxf(cx - wA * 0.5f, 0.f), 32.f);
    float y1 = fminf(fmaxf(cy - hA * 0.5f, 0.f), 32.f);
    float x2 = fminf(fmaxf(cx + wA * 0.5f, 0.f), 32.f);
    float y2 = fminf(fmaxf(cy + hA * 0.5f, 0.f), 32.f);
    float aw = x2 - x1, ah = y2 - y1;
    float acx = x1 + aw * 0.5f, acy = y1 + ah * 0.5f;
    float pcx = acx + o0 * aw, pcy = acy + o1 * ah;
    float pw = aw * expf(o2), ph = ah * expf(o3);
    float s = 1.f / (1.f + expf(-conf));

    float* o = out + (size_t)i * 5;
    o[0] = s;
    o[1] = (pcx - pw * 0.5f) * 32.f;
    o[2] = (pcy - ph * 0.5f) * 32.f;
    o[3] = (pcx + pw * 0.5f) * 32.f;
    o[4] = (pcy + ph * 0.5f) * 32.f;
}

extern "C" void kernel_launch(void* const* d_in, const int* in_sizes, int n_in,
                              void* d_out, int out_size, void* d_ws, size_t ws_size,
                              hipStream_t stream) {
    const float* x  = (const float*)d_in[0];
    const float* hw = (const float*)d_in[1];
    const float* hb = (const float*)d_in[2];
    const float* cw = (const float*)d_in[3];
    const float* cb = (const float*)d_in[4];
    const float* rw = (const float*)d_in[5];
    const float* rb = (const float*)d_in[6];
    float* out = (float*)d_out;

    char* ws = (char*)d_ws;
    ushort* xp     = (ushort*)(ws);                 // 8*34*34*2048*2  = 37,879,808
    ushort* wpk    = (ushort*)(ws + 37879808);      // 9*512*2048*2   = 18,874,368
    ushort* hidden = (ushort*)(ws + 56754176);      // 8192*512*2     =  8,388,608
    ushort* w2b    = (ushort*)(ws + 65142784);      // 48*512*2       =     49,152
    float*  g      = (float*)(ws + 65191936);       // 8192*48*4      =  1,572,864
    float*  pp     = (float*)(ws + 66764800);       // 2*8192*512*4   = 33,554,432
    const size_t WS_NEED_SPLITK = 66764800 + 33554432;   // 100,319,232

    hipLaunchKernelGGL(zero_border, dim3(132, 8), dim3(256), 0, stream, xp);
    hipLaunchKernelGGL(pack_x, dim3(16, 32, 8), dim3(256), 0, stream, x, xp);
    hipLaunchKernelGGL(pack_w, dim3(512), dim3(256), 0, stream, hw, wpk);
    hipLaunchKernelGGL(pack_w2, dim3(96), dim3(256), 0, stream, cw, rw, w2b);
    if (ws_size >= WS_NEED_SPLITK) {
        hipLaunchKernelGGL(conv_gemm_splitk, dim3(256), dim3(512), 0, stream, xp, wpk, pp);
        hipLaunchKernelGGL(reduce_bias_relu, dim3(4096), dim3(256), 0, stream, pp, hb, hidden);
    } else {
        hipLaunchKernelGGL(conv_gemm, dim3(256), dim3(256), 0, stream, xp, wpk, hb, hidden);
    }
    hipLaunchKernelGGL(gemm2, dim3(128), dim3(256), 0, stream, hidden, w2b, cb, rb, g);
    hipLaunchKernelGGL(proposals, dim3(288), dim3(256), 0, stream, g, out);
}

// Round 8
// 211.096 us; speedup vs baseline: 1.1599x; 1.0490x over previous
//
#include <hip/hip_runtime.h>
#include <hip/hip_bf16.h>

typedef __attribute__((ext_vector_type(8))) short bf16x8;
typedef __attribute__((ext_vector_type(4))) float f32x4;

#define NPIX 8192      // 8 * 32 * 32
#define HIDC 512
#define CIN  2048

// ---------- helpers ----------
__device__ __forceinline__ ushort f2b(float f) {
    union { float f; unsigned u; } v; v.f = f;
    unsigned r = v.u + 0x7fffu + ((v.u >> 16) & 1u);   // RNE
    return (ushort)(r >> 16);
}
__device__ __forceinline__ float b2f(ushort u) {
    union { unsigned u; float f; } v; v.u = ((unsigned)u) << 16; return v.f;
}

__device__ __forceinline__ void gload16(const void* g, void* l) {
    __builtin_amdgcn_global_load_lds(
        (const __attribute__((address_space(1))) void*)g,
        (__attribute__((address_space(3))) void*)l, 16, 0, 0);
}

#define WAITV0() asm volatile("s_waitcnt vmcnt(0)" ::: "memory")
#define BAR() do { asm volatile("s_barrier" ::: "memory"); \
                   __builtin_amdgcn_sched_barrier(0); } while (0)

// ---------- 0: zero only the halo border cells of xp ----------
__global__ void zero_border(ushort* __restrict__ xp) {
    int c = blockIdx.x;        // 0..131
    int b = blockIdx.y;        // 0..7
    int y, x;
    if (c < 34)      { y = 0;  x = c; }
    else if (c < 68) { y = 33; x = c - 34; }
    else if (c < 100){ y = c - 68 + 1; x = 0; }
    else             { y = c - 100 + 1; x = 33; }
    uint4* dst = (uint4*)(xp + (((size_t)b * 34 + y) * 34 + x) * CIN);
    uint4 z = {0u, 0u, 0u, 0u};
    dst[threadIdx.x] = z;
}

// ---------- 1: NCHW fp32 -> padded NHWC bf16  xp[b][y+1][x+1][c] ----------
__global__ void pack_x(const float* __restrict__ x, ushort* __restrict__ xp) {
    __shared__ float tile[64][65];
    int b  = blockIdx.z;
    int c0 = blockIdx.y * 64;
    int p0 = blockIdx.x * 64;
    int t = threadIdx.x;
    int tx = t & 63, ty = t >> 6;
    const float* src = x + ((size_t)b * CIN + c0) * 1024 + p0;
    for (int i = ty; i < 64; i += 4)
        tile[i][tx] = src[(size_t)i * 1024 + tx];
    __syncthreads();
    int ci = t & 63, pj = t >> 6;
    for (int j = pj; j < 64; j += 4) {
        int p = p0 + j;
        int y = p >> 5, xx = p & 31;
        ushort* dst = xp + (((size_t)b * 34 + y + 1) * 34 + (xx + 1)) * CIN + c0;
        dst[ci] = f2b(tile[ci][j]);
    }
}

// ---------- 2: w[n][c][ky][kx] fp32 -> wpk[tap][n][c] bf16 ----------
__global__ void pack_w(const float* __restrict__ hw, ushort* __restrict__ wpk) {
    __shared__ float ld[512 * 9];
    int n = blockIdx.x;
    int t = threadIdx.x;
    const float* src = hw + (size_t)n * (CIN * 9);
    for (int cc0 = 0; cc0 < CIN; cc0 += 512) {
        for (int i = t; i < 4608; i += 256) ld[i] = src[(size_t)cc0 * 9 + i];
        __syncthreads();
        for (int t9 = 0; t9 < 9; ++t9)
            for (int idx = t; idx < 512; idx += 256)
                wpk[((size_t)(t9 * 512 + n)) * CIN + cc0 + idx] = f2b(ld[idx * 9 + t9]);
        __syncthreads();
    }
}

// ---------- 3: conf_w/reg_w -> w2b[48][512] bf16 (rows 45..47 zero) ----------
__global__ void pack_w2(const float* __restrict__ cw, const float* __restrict__ rw,
                        ushort* __restrict__ w2b) {
    int i = blockIdx.x * 256 + threadIdx.x;
    if (i >= 48 * 512) return;
    int m = i >> 9, c = i & 511;
    float v = 0.f;
    if (m < 9) v = cw[m * 512 + c];
    else if (m < 45) v = rw[(m - 9) * 512 + c];
    w2b[i] = f2b(v);
}

// ======== 4a: conv implicit GEMM, 256x256 tile, 8 waves (2Mx4N), BK=64 ========
// Wave tile 128x64 (8x4 frags -> 43.7 FLOP per LDS byte). LDS row = 64 ch =
// 128 B = 8 chunks; stored chunk = dataChunk ^ (row&7) -> conflict-free
// ds_read_b128 (2-way max). Staging dest LINEAR, source chunk pre-XOR'd.
// 4 phases per K-tile: {ds_read frags; stage gloads (ph0:A, ph1:B); BAR;
// setprio1; 16 MFMA; setprio0; BAR}. Boundary: vmcnt(0)+BAR (loads issued
// >=3 phases earlier -> near-zero stall). Split-K x4, bf16 partials.
#define NT_TILES 72    // 4608 / 64
#define KSPLIT   4608

__launch_bounds__(512, 2)
__global__ void conv_gemm_splitk(const ushort* __restrict__ xp, const ushort* __restrict__ wpk,
                                 ushort* __restrict__ pp) {
    __shared__ __align__(16) ushort A0[256 * 64];   // 32 KB each
    __shared__ __align__(16) ushort B0[256 * 64];
    __shared__ __align__(16) ushort A1[256 * 64];
    __shared__ __align__(16) ushort B1[256 * 64];

    int t = threadIdx.x;

    // 256 blocks; xcd = bid&7 -> (nt, ks): the 32 blocks of one XCD share
    // one 2.4 MB B-panel (L2-resident) and sweep all 32 M-tiles.
    int bid = blockIdx.x;
    int xcd = bid & 7;
    int nt = xcd & 1, ks = xcd >> 1;
    int mt = bid >> 3;                 // 0..31
    int pix0 = mt * 256, n0 = nt * 256;

    int w = t >> 6, l = t & 63;
    int wr = w >> 2;                   // 0..1 : 128-row band
    int wc = w & 3;                    // 0..3 : 64-col band

    // staging geometry: thread t covers rows r0+64j, data chunk (t&7)^(r0&7)
    int r0 = t >> 3;                   // 0..63
    int dOff = ((t & 7) ^ (r0 & 7)) * 8;   // element offset of 16B data chunk

    int aRowBase[4];
#pragma unroll
    for (int j = 0; j < 4; ++j) {
        int p = pix0 + r0 + 64 * j;
        int b = p >> 10, py = (p >> 5) & 31, px = p & 31;
        aRowBase[j] = ((b * 34 + py) * 34 + px) * CIN;
    }
    int bRowBase[4];
#pragma unroll
    for (int j = 0; j < 4; ++j)
        bRowBase[j] = (n0 + r0 + 64 * j) * CIN;

    int ksBase = ks * KSPLIT;

    f32x4 zero = {0.f, 0.f, 0.f, 0.f};
    f32x4 acc[8][4];
#pragma unroll
    for (int i = 0; i < 8; ++i)
#pragma unroll
        for (int j = 0; j < 4; ++j) acc[i][j] = zero;

    // frag-read constants; row&7 == lr&7 for all frag rows
    int lr = l & 15;
    int swz0 = ((l >> 4) ^ (lr & 7)) * 16;          // k-slice 0 chunk
    int swz1 = ((4 + (l >> 4)) ^ (lr & 7)) * 16;    // k-slice 1 chunk
    int abase = (wr * 128 + lr) * 128;
    int bbase = (wc * 64 + lr) * 128;

    auto stageA = [&](int kt, ushort* As) {
        int fk = ksBase + kt * 64;
        int tap = fk >> 11, chc = fk & 2047;
        int dy = tap / 3, dx = tap - dy * 3;
        int aoff = (dy * 34 + dx) * CIN + chc + dOff;
#pragma unroll
        for (int j = 0; j < 4; ++j)
            gload16(xp + aRowBase[j] + aoff, (char*)As + (t + 512 * j) * 16);
    };
    auto stageB = [&](int kt, ushort* Bs) {
        int fk = ksBase + kt * 64;
        int tap = fk >> 11, chc = fk & 2047;
        int boff = tap * (512 * CIN) + chc + dOff;
#pragma unroll
        for (int j = 0; j < 4; ++j)
            gload16(wpk + bRowBase[j] + boff, (char*)Bs + (t + 512 * j) * 16);
    };

    bf16x8 af[4], bf0[4], bf1[4];

    auto ldA = [&](const ushort* As, int mh, int sz) {
#pragma unroll
        for (int m = 0; m < 4; ++m)
            af[m] = *(const bf16x8*)((const char*)As + abase + (mh * 4 + m) * 2048 + sz);
    };
    auto ldB = [&](const ushort* Bs, int sz, bf16x8* bf) {
#pragma unroll
        for (int ni = 0; ni < 4; ++ni)
            bf[ni] = *(const bf16x8*)((const char*)Bs + bbase + ni * 2048 + sz);
    };
    auto mm = [&](int mh, const bf16x8* bf) {
        __builtin_amdgcn_s_setprio(1);
#pragma unroll
        for (int m = 0; m < 4; ++m)
#pragma unroll
            for (int ni = 0; ni < 4; ++ni)
                acc[mh * 4 + m][ni] = __builtin_amdgcn_mfma_f32_16x16x32_bf16(
                    af[m], bf[ni], acc[mh * 4 + m][ni], 0, 0, 0);
        __builtin_amdgcn_s_setprio(0);
    };

    auto tile = [&](int i, ushort* Ac, ushort* Bc, ushort* An, ushort* Bn) {
        bool st = (i + 1 < NT_TILES);
        WAITV0(); BAR();                       // buf(i) loads landed, all waves
        // ph0 (k-slice 0, m-half 0)
        ldB(Bc, swz0, bf0); ldA(Ac, 0, swz0);
        if (st) stageA(i + 1, An);
        BAR();
        mm(0, bf0);
        BAR();
        // ph1 (k0, mh1)
        ldA(Ac, 1, swz0);
        if (st) stageB(i + 1, Bn);
        BAR();
        mm(1, bf0);
        BAR();
        // ph2 (k1, mh0)
        ldB(Bc, swz1, bf1); ldA(Ac, 0, swz1);
        BAR();
        mm(0, bf1);
        BAR();
        // ph3 (k1, mh1)
        ldA(Ac, 1, swz1);
        BAR();
        mm(1, bf1);
        // boundary of next tile supplies the trailing sync
    };

    stageA(0, A0); stageB(0, B0);
    for (int i = 0; i < NT_TILES; i += 2) {
        tile(i,     A0, B0, A1, B1);
        tile(i + 1, A1, B1, A0, B0);
    }

    // epilogue: bf16 partials
    ushort* dst = pp + (size_t)ks * (NPIX * HIDC);
    int hi = l >> 4;
#pragma unroll
    for (int mi = 0; mi < 8; ++mi) {
#pragma unroll
        for (int ni = 0; ni < 4; ++ni) {
            int col = n0 + wc * 64 + ni * 16 + lr;
#pragma unroll
            for (int r = 0; r < 4; ++r) {
                int row = pix0 + wr * 128 + mi * 16 + hi * 4 + r;
                dst[(size_t)row * HIDC + col] = f2b(acc[mi][ni][r]);
            }
        }
    }
}

// ---------- 4b: reduce 4 bf16 partials + bias + relu -> hidden bf16 ----------
__global__ void reduce_bias_relu(const ushort* __restrict__ pp, const float* __restrict__ hb,
                                 ushort* __restrict__ hidden) {
    int i = blockIdx.x * 256 + threadIdx.x;      // < 524288 (x8 elems)
    const size_t S = (size_t)NPIX * HIDC;
    bf16x8 p0 = *(const bf16x8*)(pp + (size_t)i * 8);
    bf16x8 p1 = *(const bf16x8*)(pp + S + (size_t)i * 8);
    bf16x8 p2 = *(const bf16x8*)(pp + 2 * S + (size_t)i * 8);
    bf16x8 p3 = *(const bf16x8*)(pp + 3 * S + (size_t)i * 8);
    int col0 = (i & 63) * 8;
    bf16x8 r;
#pragma unroll
    for (int j = 0; j < 8; ++j) {
        float v = b2f((ushort)p0[j]) + b2f((ushort)p1[j]) +
                  b2f((ushort)p2[j]) + b2f((ushort)p3[j]) + hb[col0 + j];
        r[j] = (short)f2b(v > 0.f ? v : 0.f);
    }
    *(bf16x8*)(hidden + (size_t)i * 8) = r;
}

// ---------- 4c: fallback single-pass conv (256 thr), if ws too small ----------
#define NKSTEP 576

__launch_bounds__(256, 1)
__global__ void conv_gemm(const ushort* __restrict__ xp, const ushort* __restrict__ wpk,
                          const float* __restrict__ hb, ushort* __restrict__ hidden) {
    __shared__ __align__(16) ushort A0[128 * 32];
    __shared__ __align__(16) ushort B0[128 * 32];
    __shared__ __align__(16) ushort A1[128 * 32];
    __shared__ __align__(16) ushort B1[128 * 32];

    int t = threadIdx.x;
    int orig = blockIdx.x;
    int xcd = orig & 7;
    int ix  = orig >> 3;
    int nb  = ix & 3;
    int pb  = (xcd << 3) + (ix >> 2);
    int n0   = nb * 128;
    int pix0 = pb * 128;

    int w = t >> 6, l = t & 63;
    int wr = w >> 1, wc = w & 1;

    int u  = t ^ ((t >> 3) & 7);
    int rA = u >> 2;
    int kA = (u & 3) * 8;

    int p1 = pix0 + rA, p2 = p1 + 64;
    int b   = p1 >> 10;
    int py1 = (p1 >> 5) & 31, px1 = p1 & 31;
    int py2 = (p2 >> 5) & 31, px2 = p2 & 31;

    size_t aBase1 = ((size_t)b * 34 + py1) * 34 + px1;
    size_t aBase2 = ((size_t)b * 34 + py2) * 34 + px2;

    f32x4 zero = {0.f, 0.f, 0.f, 0.f};
    f32x4 acc[4][4];
#pragma unroll
    for (int i = 0; i < 4; ++i)
#pragma unroll
        for (int j = 0; j < 4; ++j) acc[i][j] = zero;

    int lr = l & 15;
    int kc = l >> 4;
    int sw = ((lr * 4 + kc) ^ ((lr >> 1) & 7)) * 16;

    auto stage = [&](int kk, ushort* As, ushort* Bs) {
        int tap = kk >> 6;
        int c0 = (kk & 63) << 5;
        int dy = tap / 3, dx = tap - dy * 3;
        size_t aoff = (size_t)(dy * 34 + dx) * CIN + kA + c0;
        gload16(xp + aBase1 * CIN + aoff, (char*)As + t * 16);
        gload16(xp + aBase2 * CIN + aoff, (char*)As + 4096 + t * 16);
        const ushort* bp = wpk + ((size_t)(tap * 512) + n0 + rA) * CIN + kA + c0;
        gload16(bp, (char*)Bs + t * 16);
        gload16(bp + (size_t)64 * CIN, (char*)Bs + 4096 + t * 16);
    };

    auto compute = [&](const ushort* As, const ushort* Bs) {
        const char* ab = (const char*)As + wr * 4096 + sw;
        const char* bb = (const char*)Bs + wc * 4096 + sw;
        bf16x8 af[4], bfr[4];
#pragma unroll
        for (int mi = 0; mi < 4; ++mi)
            af[mi] = *(const bf16x8*)(ab + mi * 1024);
#pragma unroll
        for (int ni = 0; ni < 4; ++ni)
            bfr[ni] = *(const bf16x8*)(bb + ni * 1024);
#pragma unroll
        for (int mi = 0; mi < 4; ++mi)
#pragma unroll
            for (int ni = 0; ni < 4; ++ni)
                acc[mi][ni] = __builtin_amdgcn_mfma_f32_16x16x32_bf16(
                    af[mi], bfr[ni], acc[mi][ni], 0, 0, 0);
    };

    stage(0, A0, B0);
    __syncthreads();
    for (int kk = 0; kk < NKSTEP; kk += 2) {
        if (kk + 1 < NKSTEP) stage(kk + 1, A1, B1);
        compute(A0, B0);
        __syncthreads();
        if (kk + 2 < NKSTEP) stage(kk + 2, A0, B0);
        compute(A1, B1);
        __syncthreads();
    }

    int lr4 = (l >> 4) * 4;
#pragma unroll
    for (int mi = 0; mi < 4; ++mi) {
#pragma unroll
        for (int ni = 0; ni < 4; ++ni) {
            int col = n0 + wc * 64 + ni * 16 + lr;
            float bias = hb[col];
#pragma unroll
            for (int r = 0; r < 4; ++r) {
                int row = pix0 + wr * 64 + mi * 16 + lr4 + r;
                float v = acc[mi][ni][r] + bias;
                v = v > 0.f ? v : 0.f;
                hidden[(size_t)row * HIDC + col] = f2b(v);
            }
        }
    }
}

// ---------- 5: 1x1 convs as GEMM (N=48 incl pad), bias -> g fp32 [8192][48] ----------
__launch_bounds__(256)
__global__ void gemm2(const ushort* __restrict__ hidden, const ushort* __restrict__ w2b,
                      const float* __restrict__ cb, const float* __restrict__ rb,
                      float* __restrict__ g) {
    __shared__ __align__(16) ushort W2[48 * 520];
    int t = threadIdx.x;
    const unsigned* src = (const unsigned*)w2b;
    unsigned* dstW = (unsigned*)&W2[0];
    for (int i = t; i < 12288; i += 256) {
        int m = i >> 8, c2 = i & 255;
        dstW[m * 260 + c2] = src[i];
    }
    __syncthreads();
    int w = t >> 6, l = t & 63;
    int p0 = blockIdx.x * 64 + w * 16;
    int lr = l & 15, lk = (l >> 4) * 8;
    f32x4 zero = {0.f, 0.f, 0.f, 0.f};
    f32x4 acc[3] = {zero, zero, zero};
    const ushort* hrow = hidden + (size_t)(p0 + lr) * HIDC + lk;
#pragma unroll 4
    for (int k0 = 0; k0 < 16; ++k0) {
        bf16x8 a = *(const bf16x8*)(hrow + k0 * 32);
#pragma unroll
        for (int ni = 0; ni < 3; ++ni) {
            bf16x8 bb = *(const bf16x8*)&W2[(ni * 16 + lr) * 520 + k0 * 32 + lk];
            acc[ni] = __builtin_amdgcn_mfma_f32_16x16x32_bf16(a, bb, acc[ni], 0, 0, 0);
        }
    }
    int lr4 = (l >> 4) * 4;
#pragma unroll
    for (int ni = 0; ni < 3; ++ni) {
        int m = ni * 16 + lr;
        float bias = (m < 9) ? cb[m] : ((m < 45) ? rb[m - 9] : 0.f);
#pragma unroll
        for (int r = 0; r < 4; ++r) {
            int p = p0 + lr4 + r;
            g[(size_t)p * 48 + m] = acc[ni][r] + bias;
        }
    }
}

// ---------- 6: proposal math ----------
__global__ void proposals(const float* __restrict__ g, float* __restrict__ out) {
    int i = blockIdx.x * 256 + threadIdx.x;
    if (i >= NPIX * 9) return;
    int p = i / 9, a = i - p * 9;
    int y = (p >> 5) & 31, x = p & 31;
    int si = a / 3, ri = a - si * 3;
    float hA = 2.f * (float)(si + 1);
    float wA = (float)((si + 1) * (ri + 1));

    const float* gp = g + (size_t)p * 48;
    float conf = gp[a];
    float o0 = gp[9 + a * 4 + 0];
    float o1 = gp[9 + a * 4 + 1];
    float o2 = gp[9 + a * 4 + 2];
    float o3 = gp[9 + a * 4 + 3];

    float cx = x + 0.5f, cy = y + 0.5f;
    float x1 = fminf(fmaxf(cx - wA * 0.5f, 0.f), 32.f);
    float y1 = fminf(fmaxf(cy - hA * 0.5f, 0.f), 32.f);
    float x2 = fminf(fmaxf(cx + wA * 0.5f, 0.f), 32.f);
    float y2 = fminf(fmaxf(cy + hA * 0.5f, 0.f), 32.f);
    float aw = x2 - x1, ah = y2 - y1;
    float acx = x1 + aw * 0.5f, acy = y1 + ah * 0.5f;
    float pcx = acx + o0 * aw, pcy = acy + o1 * ah;
    float pw = aw * expf(o2), ph = ah * expf(o3);
    float s = 1.f / (1.f + expf(-conf));

    float* o = out + (size_t)i * 5;
    o[0] = s;
    o[1] = (pcx - pw * 0.5f) * 32.f;
    o[2] = (pcy - ph * 0.5f) * 32.f;
    o[3] = (pcx + pw * 0.5f) * 32.f;
    o[4] = (pcy + ph * 0.5f) * 32.f;
}

extern "C" void kernel_launch(void* const* d_in, const int* in_sizes, int n_in,
                              void* d_out, int out_size, void* d_ws, size_t ws_size,
                              hipStream_t stream) {
    const float* x  = (const float*)d_in[0];
    const float* hw = (const float*)d_in[1];
    const float* hb = (const float*)d_in[2];
    const float* cw = (const float*)d_in[3];
    const float* cb = (const float*)d_in[4];
    const float* rw = (const float*)d_in[5];
    const float* rb = (const float*)d_in[6];
    float* out = (float*)d_out;

    char* ws = (char*)d_ws;
    ushort* xp     = (ushort*)(ws);                 // 8*34*34*2048*2  = 37,879,808
    ushort* wpk    = (ushort*)(ws + 37879808);      // 9*512*2048*2   = 18,874,368
    ushort* hidden = (ushort*)(ws + 56754176);      // 8192*512*2     =  8,388,608
    ushort* w2b    = (ushort*)(ws + 65142784);      // 48*512*2       =     49,152
    float*  g      = (float*)(ws + 65191936);       // 8192*48*4      =  1,572,864
    ushort* pp     = (ushort*)(ws + 66764800);      // 4*8192*512*2   = 33,554,432
    const size_t WS_NEED_SPLITK = 66764800 + 33554432;   // 100,319,232

    hipLaunchKernelGGL(zero_border, dim3(132, 8), dim3(256), 0, stream, xp);
    hipLaunchKernelGGL(pack_x, dim3(16, 32, 8), dim3(256), 0, stream, x, xp);
    hipLaunchKernelGGL(pack_w, dim3(512), dim3(256), 0, stream, hw, wpk);
    hipLaunchKernelGGL(pack_w2, dim3(96), dim3(256), 0, stream, cw, rw, w2b);
    if (ws_size >= WS_NEED_SPLITK) {
        hipLaunchKernelGGL(conv_gemm_splitk, dim3(256), dim3(512), 0, stream, xp, wpk, pp);
        hipLaunchKernelGGL(reduce_bias_relu, dim3(2048), dim3(256), 0, stream, pp, hb, hidden);
    } else {
        hipLaunchKernelGGL(conv_gemm, dim3(256), dim3(256), 0, stream, xp, wpk, hb, hidden);
    }
    hipLaunchKernelGGL(gemm2, dim3(128), dim3(256), 0, stream, hidden, w2b, cb, rb, g);
    hipLaunchKernelGGL(proposals, dim3(288), dim3(256), 0, stream, g, out);
}

// Round 9
// 191.333 us; speedup vs baseline: 1.2797x; 1.1033x over previous
//
#include <hip/hip_runtime.h>
#include <hip/hip_bf16.h>

typedef __attribute__((ext_vector_type(8))) short bf16x8;
typedef __attribute__((ext_vector_type(4))) float f32x4;

#define NPIX 8192      // 8 * 32 * 32
#define HIDC 512
#define CIN  2048

// ---------- helpers ----------
__device__ __forceinline__ ushort f2b(float f) {
    union { float f; unsigned u; } v; v.f = f;
    unsigned r = v.u + 0x7fffu + ((v.u >> 16) & 1u);   // RNE
    return (ushort)(r >> 16);
}
__device__ __forceinline__ float b2f(ushort u) {
    union { unsigned u; float f; } v; v.u = ((unsigned)u) << 16; return v.f;
}

__device__ __forceinline__ void gload16(const void* g, void* l) {
    __builtin_amdgcn_global_load_lds(
        (const __attribute__((address_space(1))) void*)g,
        (__attribute__((address_space(3))) void*)l, 16, 0, 0);
}

#define WAITV0() asm volatile("s_waitcnt vmcnt(0)" ::: "memory")
#define BAR() do { asm volatile("s_barrier" ::: "memory"); \
                   __builtin_amdgcn_sched_barrier(0); } while (0)
#define SCHED() __builtin_amdgcn_sched_barrier(0)

// ---------- 0: zero only the halo border cells of xp ----------
__global__ void zero_border(ushort* __restrict__ xp) {
    int c = blockIdx.x;        // 0..131
    int b = blockIdx.y;        // 0..7
    int y, x;
    if (c < 34)      { y = 0;  x = c; }
    else if (c < 68) { y = 33; x = c - 34; }
    else if (c < 100){ y = c - 68 + 1; x = 0; }
    else             { y = c - 100 + 1; x = 33; }
    uint4* dst = (uint4*)(xp + (((size_t)b * 34 + y) * 34 + x) * CIN);
    uint4 z = {0u, 0u, 0u, 0u};
    dst[threadIdx.x] = z;
}

// ---------- 1: NCHW fp32 -> padded NHWC bf16  xp[b][y+1][x+1][c] ----------
__global__ void pack_x(const float* __restrict__ x, ushort* __restrict__ xp) {
    __shared__ float tile[64][65];
    int b  = blockIdx.z;
    int c0 = blockIdx.y * 64;
    int p0 = blockIdx.x * 64;
    int t = threadIdx.x;
    int tx = t & 63, ty = t >> 6;
    const float* src = x + ((size_t)b * CIN + c0) * 1024 + p0;
    for (int i = ty; i < 64; i += 4)
        tile[i][tx] = src[(size_t)i * 1024 + tx];
    __syncthreads();
    int ci = t & 63, pj = t >> 6;
    for (int j = pj; j < 64; j += 4) {
        int p = p0 + j;
        int y = p >> 5, xx = p & 31;
        ushort* dst = xp + (((size_t)b * 34 + y + 1) * 34 + (xx + 1)) * CIN + c0;
        dst[ci] = f2b(tile[ci][j]);
    }
}

// ---------- 2: w[n][c][ky][kx] fp32 -> wpk[tap][n][c] bf16 ----------
__global__ void pack_w(const float* __restrict__ hw, ushort* __restrict__ wpk) {
    __shared__ float ld[512 * 9];
    int n = blockIdx.x;
    int t = threadIdx.x;
    const float* src = hw + (size_t)n * (CIN * 9);
    for (int cc0 = 0; cc0 < CIN; cc0 += 512) {
        for (int i = t; i < 4608; i += 256) ld[i] = src[(size_t)cc0 * 9 + i];
        __syncthreads();
        for (int t9 = 0; t9 < 9; ++t9)
            for (int idx = t; idx < 512; idx += 256)
                wpk[((size_t)(t9 * 512 + n)) * CIN + cc0 + idx] = f2b(ld[idx * 9 + t9]);
        __syncthreads();
    }
}

// ---------- 3: conf_w/reg_w -> w2b[48][512] bf16 (rows 45..47 zero) ----------
__global__ void pack_w2(const float* __restrict__ cw, const float* __restrict__ rw,
                        ushort* __restrict__ w2b) {
    int i = blockIdx.x * 256 + threadIdx.x;
    if (i >= 48 * 512) return;
    int m = i >> 9, c = i & 511;
    float v = 0.f;
    if (m < 9) v = cw[m * 512 + c];
    else if (m < 45) v = rw[(m - 9) * 512 + c];
    w2b[i] = f2b(v);
}

// ======== 4a: conv implicit GEMM, 256x256 tile, 8 waves (2Mx4N), BK=64 ========
// One s_barrier + vmcnt(0) per K-tile (intra-tile barriers removed: all
// intra-tile reads are read-after-read; stage(i+1) targets the other buffer,
// whose readers finished before the tile-entry barrier). sched_barrier(0)
// fences keep the per-wave read/MFMA interleave; natural wave skew overlaps
// the LDS and MFMA pipes; setprio biases the CU scheduler toward MFMA.
// LDS chunk swizzle: stored chunk = dataChunk ^ (row&7); dest linear,
// source pre-XOR'd, read applies XOR (conflict-free, verified r3-r8).
#define NT_TILES 72    // 4608 / 64
#define KSPLIT   4608

__launch_bounds__(512, 2)
__global__ void conv_gemm_splitk(const ushort* __restrict__ xp, const ushort* __restrict__ wpk,
                                 ushort* __restrict__ pp) {
    __shared__ __align__(16) ushort A0[256 * 64];   // 32 KB each
    __shared__ __align__(16) ushort B0[256 * 64];
    __shared__ __align__(16) ushort A1[256 * 64];
    __shared__ __align__(16) ushort B1[256 * 64];

    int t = threadIdx.x;

    // 256 blocks; xcd = bid&7 -> (nt, ks): 32 blocks of one XCD share one
    // 2.4 MB B-panel (L2-resident) and sweep all 32 M-tiles.
    int bid = blockIdx.x;
    int xcd = bid & 7;
    int nt = xcd & 1, ks = xcd >> 1;
    int mt = bid >> 3;                 // 0..31
    int pix0 = mt * 256, n0 = nt * 256;

    int w = t >> 6, l = t & 63;
    int wr = w >> 2;                   // 0..1 : 128-row band
    int wc = w & 3;                    // 0..3 : 64-col band

    // staging geometry: thread t covers rows r0+64j, data chunk (t&7)^(r0&7)
    int r0 = t >> 3;                   // 0..63
    int dOff = ((t & 7) ^ (r0 & 7)) * 8;

    int aRowBase[4];
#pragma unroll
    for (int j = 0; j < 4; ++j) {
        int p = pix0 + r0 + 64 * j;
        int b = p >> 10, py = (p >> 5) & 31, px = p & 31;
        aRowBase[j] = ((b * 34 + py) * 34 + px) * CIN;
    }
    int bRowBase[4];
#pragma unroll
    for (int j = 0; j < 4; ++j)
        bRowBase[j] = (n0 + r0 + 64 * j) * CIN;

    int ksBase = ks * KSPLIT;

    f32x4 zero = {0.f, 0.f, 0.f, 0.f};
    f32x4 acc[8][4];
#pragma unroll
    for (int i = 0; i < 8; ++i)
#pragma unroll
        for (int j = 0; j < 4; ++j) acc[i][j] = zero;

    int lr = l & 15;
    int swz0 = ((l >> 4) ^ (lr & 7)) * 16;          // k-slice 0 chunk
    int swz1 = ((4 + (l >> 4)) ^ (lr & 7)) * 16;    // k-slice 1 chunk
    int abase = (wr * 128 + lr) * 128;
    int bbase = (wc * 64 + lr) * 128;

    auto stageA = [&](int kt, ushort* As) {
        int fk = ksBase + kt * 64;
        int tap = fk >> 11, chc = fk & 2047;
        int dy = tap / 3, dx = tap - dy * 3;
        int aoff = (dy * 34 + dx) * CIN + chc + dOff;
#pragma unroll
        for (int j = 0; j < 4; ++j)
            gload16(xp + aRowBase[j] + aoff, (char*)As + (t + 512 * j) * 16);
    };
    auto stageB = [&](int kt, ushort* Bs) {
        int fk = ksBase + kt * 64;
        int tap = fk >> 11, chc = fk & 2047;
        int boff = tap * (512 * CIN) + chc + dOff;
#pragma unroll
        for (int j = 0; j < 4; ++j)
            gload16(wpk + bRowBase[j] + boff, (char*)Bs + (t + 512 * j) * 16);
    };

    bf16x8 af[4], bf0[4], bf1[4];

    auto ldA = [&](const ushort* As, int mh, int sz) {
#pragma unroll
        for (int m = 0; m < 4; ++m)
            af[m] = *(const bf16x8*)((const char*)As + abase + (mh * 4 + m) * 2048 + sz);
    };
    auto ldB = [&](const ushort* Bs, int sz, bf16x8* bf) {
#pragma unroll
        for (int ni = 0; ni < 4; ++ni)
            bf[ni] = *(const bf16x8*)((const char*)Bs + bbase + ni * 2048 + sz);
    };
    auto mm = [&](int mh, const bf16x8* bf) {
        __builtin_amdgcn_s_setprio(1);
#pragma unroll
        for (int m = 0; m < 4; ++m)
#pragma unroll
            for (int ni = 0; ni < 4; ++ni)
                acc[mh * 4 + m][ni] = __builtin_amdgcn_mfma_f32_16x16x32_bf16(
                    af[m], bf[ni], acc[mh * 4 + m][ni], 0, 0, 0);
        __builtin_amdgcn_s_setprio(0);
    };

    auto tile = [&](int i, ushort* Ac, ushort* Bc, ushort* An, ushort* Bn) {
        bool st = (i + 1 < NT_TILES);
        WAITV0(); BAR();                       // buf(i) visible to all waves
        // ph0 (k0, mh0) + A-prefetch
        ldB(Bc, swz0, bf0); ldA(Ac, 0, swz0);
        if (st) stageA(i + 1, An);
        SCHED();
        mm(0, bf0);
        SCHED();
        // ph1 (k0, mh1) + B-prefetch
        ldA(Ac, 1, swz0);
        if (st) stageB(i + 1, Bn);
        SCHED();
        mm(1, bf0);
        SCHED();
        // ph2 (k1, mh0)
        ldB(Bc, swz1, bf1); ldA(Ac, 0, swz1);
        SCHED();
        mm(0, bf1);
        SCHED();
        // ph3 (k1, mh1)
        ldA(Ac, 1, swz1);
        SCHED();
        mm(1, bf1);
        SCHED();
    };

    stageA(0, A0); stageB(0, B0);
    for (int i = 0; i < NT_TILES; i += 2) {
        tile(i,     A0, B0, A1, B1);
        tile(i + 1, A1, B1, A0, B0);
    }

    // epilogue: bf16 partials
    ushort* dst = pp + (size_t)ks * (NPIX * HIDC);
    int hi = l >> 4;
#pragma unroll
    for (int mi = 0; mi < 8; ++mi) {
#pragma unroll
        for (int ni = 0; ni < 4; ++ni) {
            int col = n0 + wc * 64 + ni * 16 + lr;
#pragma unroll
            for (int r = 0; r < 4; ++r) {
                int row = pix0 + wr * 128 + mi * 16 + hi * 4 + r;
                dst[(size_t)row * HIDC + col] = f2b(acc[mi][ni][r]);
            }
        }
    }
}

// ---------- 4c: fallback single-pass conv (256 thr), if ws too small ----------
#define NKSTEP 576

__launch_bounds__(256, 1)
__global__ void conv_gemm(const ushort* __restrict__ xp, const ushort* __restrict__ wpk,
                          const float* __restrict__ hb, ushort* __restrict__ hidden) {
    __shared__ __align__(16) ushort A0[128 * 32];
    __shared__ __align__(16) ushort B0[128 * 32];
    __shared__ __align__(16) ushort A1[128 * 32];
    __shared__ __align__(16) ushort B1[128 * 32];

    int t = threadIdx.x;
    int orig = blockIdx.x;
    int xcd = orig & 7;
    int ix  = orig >> 3;
    int nb  = ix & 3;
    int pb  = (xcd << 3) + (ix >> 2);
    int n0   = nb * 128;
    int pix0 = pb * 128;

    int w = t >> 6, l = t & 63;
    int wr = w >> 1, wc = w & 1;

    int u  = t ^ ((t >> 3) & 7);
    int rA = u >> 2;
    int kA = (u & 3) * 8;

    int p1 = pix0 + rA, p2 = p1 + 64;
    int b   = p1 >> 10;
    int py1 = (p1 >> 5) & 31, px1 = p1 & 31;
    int py2 = (p2 >> 5) & 31, px2 = p2 & 31;

    size_t aBase1 = ((size_t)b * 34 + py1) * 34 + px1;
    size_t aBase2 = ((size_t)b * 34 + py2) * 34 + px2;

    f32x4 zero = {0.f, 0.f, 0.f, 0.f};
    f32x4 acc[4][4];
#pragma unroll
    for (int i = 0; i < 4; ++i)
#pragma unroll
        for (int j = 0; j < 4; ++j) acc[i][j] = zero;

    int lr = l & 15;
    int kc = l >> 4;
    int sw = ((lr * 4 + kc) ^ ((lr >> 1) & 7)) * 16;

    auto stage = [&](int kk, ushort* As, ushort* Bs) {
        int tap = kk >> 6;
        int c0 = (kk & 63) << 5;
        int dy = tap / 3, dx = tap - dy * 3;
        size_t aoff = (size_t)(dy * 34 + dx) * CIN + kA + c0;
        gload16(xp + aBase1 * CIN + aoff, (char*)As + t * 16);
        gload16(xp + aBase2 * CIN + aoff, (char*)As + 4096 + t * 16);
        const ushort* bp = wpk + ((size_t)(tap * 512) + n0 + rA) * CIN + kA + c0;
        gload16(bp, (char*)Bs + t * 16);
        gload16(bp + (size_t)64 * CIN, (char*)Bs + 4096 + t * 16);
    };

    auto compute = [&](const ushort* As, const ushort* Bs) {
        const char* ab = (const char*)As + wr * 4096 + sw;
        const char* bb = (const char*)Bs + wc * 4096 + sw;
        bf16x8 af[4], bfr[4];
#pragma unroll
        for (int mi = 0; mi < 4; ++mi)
            af[mi] = *(const bf16x8*)(ab + mi * 1024);
#pragma unroll
        for (int ni = 0; ni < 4; ++ni)
            bfr[ni] = *(const bf16x8*)(bb + ni * 1024);
#pragma unroll
        for (int mi = 0; mi < 4; ++mi)
#pragma unroll
            for (int ni = 0; ni < 4; ++ni)
                acc[mi][ni] = __builtin_amdgcn_mfma_f32_16x16x32_bf16(
                    af[mi], bfr[ni], acc[mi][ni], 0, 0, 0);
    };

    stage(0, A0, B0);
    __syncthreads();
    for (int kk = 0; kk < NKSTEP; kk += 2) {
        if (kk + 1 < NKSTEP) stage(kk + 1, A1, B1);
        compute(A0, B0);
        __syncthreads();
        if (kk + 2 < NKSTEP) stage(kk + 2, A0, B0);
        compute(A1, B1);
        __syncthreads();
    }

    int lr4 = (l >> 4) * 4;
#pragma unroll
    for (int mi = 0; mi < 4; ++mi) {
#pragma unroll
        for (int ni = 0; ni < 4; ++ni) {
            int col = n0 + wc * 64 + ni * 16 + lr;
            float bias = hb[col];
#pragma unroll
            for (int r = 0; r < 4; ++r) {
                int row = pix0 + wr * 64 + mi * 16 + lr4 + r;
                float v = acc[mi][ni][r] + bias;
                v = v > 0.f ? v : 0.f;
                hidden[(size_t)row * HIDC + col] = f2b(v);
            }
        }
    }
}

// ---------- 5a: FUSED reduce(4 partials)+bias+relu + 1x1 convs -> g ----------
__launch_bounds__(256)
__global__ void gemm2f(const ushort* __restrict__ pp, const float* __restrict__ hb,
                       const ushort* __restrict__ w2b,
                       const float* __restrict__ cb, const float* __restrict__ rb,
                       float* __restrict__ g) {
    __shared__ __align__(16) ushort W2[48 * 520];
    int t = threadIdx.x;
    const unsigned* src = (const unsigned*)w2b;
    unsigned* dstW = (unsigned*)&W2[0];
    for (int i = t; i < 12288; i += 256) {
        int m = i >> 8, c2 = i & 255;
        dstW[m * 260 + c2] = src[i];
    }
    __syncthreads();
    int w = t >> 6, l = t & 63;
    int p0 = blockIdx.x * 64 + w * 16;
    int lr = l & 15, lk = (l >> 4) * 8;
    const size_t S = (size_t)NPIX * HIDC;
    f32x4 zero = {0.f, 0.f, 0.f, 0.f};
    f32x4 acc[3] = {zero, zero, zero};
    const ushort* hrow = pp + (size_t)(p0 + lr) * HIDC + lk;
#pragma unroll 4
    for (int k0 = 0; k0 < 16; ++k0) {
        bf16x8 a0 = *(const bf16x8*)(hrow + k0 * 32);
        bf16x8 a1 = *(const bf16x8*)(hrow + S + k0 * 32);
        bf16x8 a2 = *(const bf16x8*)(hrow + 2 * S + k0 * 32);
        bf16x8 a3 = *(const bf16x8*)(hrow + 3 * S + k0 * 32);
        bf16x8 a;
#pragma unroll
        for (int j = 0; j < 8; ++j) {
            float v = b2f((ushort)a0[j]) + b2f((ushort)a1[j]) +
                      b2f((ushort)a2[j]) + b2f((ushort)a3[j]) + hb[k0 * 32 + lk + j];
            a[j] = (short)f2b(v > 0.f ? v : 0.f);
        }
#pragma unroll
        for (int ni = 0; ni < 3; ++ni) {
            bf16x8 bb = *(const bf16x8*)&W2[(ni * 16 + lr) * 520 + k0 * 32 + lk];
            acc[ni] = __builtin_amdgcn_mfma_f32_16x16x32_bf16(a, bb, acc[ni], 0, 0, 0);
        }
    }
    int lr4 = (l >> 4) * 4;
#pragma unroll
    for (int ni = 0; ni < 3; ++ni) {
        int m = ni * 16 + lr;
        float bias = (m < 9) ? cb[m] : ((m < 45) ? rb[m - 9] : 0.f);
#pragma unroll
        for (int r = 0; r < 4; ++r) {
            int p = p0 + lr4 + r;
            g[(size_t)p * 48 + m] = acc[ni][r] + bias;
        }
    }
}

// ---------- 5b: plain gemm2 from hidden (fallback path) ----------
__launch_bounds__(256)
__global__ void gemm2(const ushort* __restrict__ hidden, const ushort* __restrict__ w2b,
                      const float* __restrict__ cb, const float* __restrict__ rb,
                      float* __restrict__ g) {
    __shared__ __align__(16) ushort W2[48 * 520];
    int t = threadIdx.x;
    const unsigned* src = (const unsigned*)w2b;
    unsigned* dstW = (unsigned*)&W2[0];
    for (int i = t; i < 12288; i += 256) {
        int m = i >> 8, c2 = i & 255;
        dstW[m * 260 + c2] = src[i];
    }
    __syncthreads();
    int w = t >> 6, l = t & 63;
    int p0 = blockIdx.x * 64 + w * 16;
    int lr = l & 15, lk = (l >> 4) * 8;
    f32x4 zero = {0.f, 0.f, 0.f, 0.f};
    f32x4 acc[3] = {zero, zero, zero};
    const ushort* hrow = hidden + (size_t)(p0 + lr) * HIDC + lk;
#pragma unroll 4
    for (int k0 = 0; k0 < 16; ++k0) {
        bf16x8 a = *(const bf16x8*)(hrow + k0 * 32);
#pragma unroll
        for (int ni = 0; ni < 3; ++ni) {
            bf16x8 bb = *(const bf16x8*)&W2[(ni * 16 + lr) * 520 + k0 * 32 + lk];
            acc[ni] = __builtin_amdgcn_mfma_f32_16x16x32_bf16(a, bb, acc[ni], 0, 0, 0);
        }
    }
    int lr4 = (l >> 4) * 4;
#pragma unroll
    for (int ni = 0; ni < 3; ++ni) {
        int m = ni * 16 + lr;
        float bias = (m < 9) ? cb[m] : ((m < 45) ? rb[m - 9] : 0.f);
#pragma unroll
        for (int r = 0; r < 4; ++r) {
            int p = p0 + lr4 + r;
            g[(size_t)p * 48 + m] = acc[ni][r] + bias;
        }
    }
}

// ---------- 6: proposal math ----------
__global__ void proposals(const float* __restrict__ g, float* __restrict__ out) {
    int i = blockIdx.x * 256 + threadIdx.x;
    if (i >= NPIX * 9) return;
    int p = i / 9, a = i - p * 9;
    int y = (p >> 5) & 31, x = p & 31;
    int si = a / 3, ri = a - si * 3;
    float hA = 2.f * (float)(si + 1);
    float wA = (float)((si + 1) * (ri + 1));

    const float* gp = g + (size_t)p * 48;
    float conf = gp[a];
    float o0 = gp[9 + a * 4 + 0];
    float o1 = gp[9 + a * 4 + 1];
    float o2 = gp[9 + a * 4 + 2];
    float o3 = gp[9 + a * 4 + 3];

    float cx = x + 0.5f, cy = y + 0.5f;
    float x1 = fminf(fmaxf(cx - wA * 0.5f, 0.f), 32.f);
    float y1 = fminf(fmaxf(cy - hA * 0.5f, 0.f), 32.f);
    float x2 = fminf(fmaxf(cx + wA * 0.5f, 0.f), 32.f);
    float y2 = fminf(fmaxf(cy + hA * 0.5f, 0.f), 32.f);
    float aw = x2 - x1, ah = y2 - y1;
    float acx = x1 + aw * 0.5f, acy = y1 + ah * 0.5f;
    float pcx = acx + o0 * aw, pcy = acy + o1 * ah;
    float pw = aw * expf(o2), ph = ah * expf(o3);
    float s = 1.f / (1.f + expf(-conf));

    float* o = out + (size_t)i * 5;
    o[0] = s;
    o[1] = (pcx - pw * 0.5f) * 32.f;
    o[2] = (pcy - ph * 0.5f) * 32.f;
    o[3] = (pcx + pw * 0.5f) * 32.f;
    o[4] = (pcy + ph * 0.5f) * 32.f;
}

extern "C" void kernel_launch(void* const* d_in, const int* in_sizes, int n_in,
                              void* d_out, int out_size, void* d_ws, size_t ws_size,
                              hipStream_t stream) {
    const float* x  = (const float*)d_in[0];
    const float* hw = (const float*)d_in[1];
    const float* hb = (const float*)d_in[2];
    const float* cw = (const float*)d_in[3];
    const float* cb = (const float*)d_in[4];
    const float* rw = (const float*)d_in[5];
    const float* rb = (const float*)d_in[6];
    float* out = (float*)d_out;

    char* ws = (char*)d_ws;
    ushort* xp     = (ushort*)(ws);                 // 8*34*34*2048*2  = 37,879,808
    ushort* wpk    = (ushort*)(ws + 37879808);      // 9*512*2048*2   = 18,874,368
    ushort* hidden = (ushort*)(ws + 56754176);      // 8192*512*2     =  8,388,608
    ushort* w2b    = (ushort*)(ws + 65142784);      // 48*512*2       =     49,152
    float*  g      = (float*)(ws + 65191936);       // 8192*48*4      =  1,572,864
    ushort* pp     = (ushort*)(ws + 66764800);      // 4*8192*512*2   = 33,554,432
    const size_t WS_NEED_SPLITK = 66764800 + 33554432;   // 100,319,232

    hipLaunchKernelGGL(zero_border, dim3(132, 8), dim3(256), 0, stream, xp);
    hipLaunchKernelGGL(pack_x, dim3(16, 32, 8), dim3(256), 0, stream, x, xp);
    hipLaunchKernelGGL(pack_w, dim3(512), dim3(256), 0, stream, hw, wpk);
    hipLaunchKernelGGL(pack_w2, dim3(96), dim3(256), 0, stream, cw, rw, w2b);
    if (ws_size >= WS_NEED_SPLITK) {
        hipLaunchKernelGGL(conv_gemm_splitk, dim3(256), dim3(512), 0, stream, xp, wpk, pp);
        hipLaunchKernelGGL(gemm2f, dim3(128), dim3(256), 0, stream, pp, hb, w2b, cb, rb, g);
    } else {
        hipLaunchKernelGGL(conv_gemm, dim3(256), dim3(256), 0, stream, xp, wpk, hb, hidden);
        hipLaunchKernelGGL(gemm2, dim3(128), dim3(256), 0, stream, hidden, w2b, cb, rb, g);
    }
    hipLaunchKernelGGL(proposals, dim3(288), dim3(256), 0, stream, g, out);
}